// Round 1
// 341.396 us; speedup vs baseline: 1.0088x; 1.0088x over previous
//
#include <hip/hip_runtime.h>

// N=50000, D=128 (both layers), K=256, EH=500000, ES=250000.
#define D_FEAT 128
#define K_DIM  256
#define EPB 4096
#define PADL 136   // LDS leading dim (ushorts) for the 32x128 epilogue tile; 272B row, 16B-aligned

typedef __attribute__((ext_vector_type(8))) short bf16x8;
typedef __attribute__((ext_vector_type(4))) float f32x4;

__device__ __forceinline__ unsigned short f2b(float f) {
    union { float f; unsigned u; } cv; cv.f = f;
    return (unsigned short)((cv.u + 0x7fffu + ((cv.u >> 16) & 1u)) >> 16);
}

__device__ __forceinline__ unsigned pack2(float lo, float hi) {
    return (unsigned)f2b(lo) | ((unsigned)f2b(hi) << 16);
}

__device__ __forceinline__ uint4 pack8(float4 a, float4 b) {
    return make_uint4(pack2(a.x, a.y), pack2(a.z, a.w), pack2(b.x, b.y), pack2(b.z, b.w));
}

// unpack uint4 = 8 bf16 (low half of word = even element) and accumulate
__device__ __forceinline__ void addu4(float* a, uint4 v) {
    union { unsigned u; float f; } c;
    c.u = v.x << 16;         a[0] += c.f;
    c.u = v.x & 0xffff0000u; a[1] += c.f;
    c.u = v.y << 16;         a[2] += c.f;
    c.u = v.y & 0xffff0000u; a[3] += c.f;
    c.u = v.z << 16;         a[4] += c.f;
    c.u = v.z & 0xffff0000u; a[5] += c.f;
    c.u = v.w << 16;         a[6] += c.f;
    c.u = v.w & 0xffff0000u; a[7] += c.f;
}

__device__ __forceinline__ float blo(unsigned u) { union { unsigned u; float f; } c; c.u = u << 16; return c.f; }
__device__ __forceinline__ float bhi(unsigned u) { union { unsigned u; float f; } c; c.u = u & 0xffff0000u; return c.f; }

// edge-array offset within the concatenated [H0|S0|H1|S1] space
__device__ __forceinline__ long yoff(int y, int EH, int ES) {
    return (long)((y + 1) >> 1) * EH + (long)(y >> 1) * ES;
}

// ---------------- bucket-level CSR build (both layers; y in 0..3) ----------------

__global__ __launch_bounds__(256)
void histB(const int* __restrict__ hd0, const int* __restrict__ sd0,
           const int* __restrict__ hd1, const int* __restrict__ sd1,
           int EH, int ES, int* __restrict__ bucketCnt, int nb2) {
    int y = blockIdx.y;
    const int* d = (y == 0) ? hd0 : (y == 1) ? sd0 : (y == 2) ? hd1 : sd1;
    int E = (y & 1) ? ES : EH;
    __shared__ int cnt[256];
    int t = threadIdx.x;
    cnt[t] = 0;
    __syncthreads();
    int i0 = blockIdx.x * EPB;
    #pragma unroll
    for (int j = 0; j < 16; ++j) {
        int i = i0 + j * 256 + t;
        if (i < E) atomicAdd(&cnt[d[i] >> 8], 1);
    }
    __syncthreads();
    if (t < nb2 && cnt[t] > 0) atomicAdd(&bucketCnt[y * nb2 + t], cnt[t]);
}

__global__ __launch_bounds__(64)
void scanBuckets(const int* __restrict__ bucketCnt, int* __restrict__ rpBucket,
                 int* __restrict__ bcur, int nb2) {
    int t = threadIdx.x;
    if (t < 4) {
        int run = 0;
        for (int i = 0; i < nb2; ++i) {
            rpBucket[t * (nb2 + 1) + i] = run;
            bcur[t * nb2 + i] = run;
            run += bucketCnt[t * nb2 + i];
        }
        rpBucket[t * (nb2 + 1) + nb2] = run;
    }
}

// Record: src (24 bits) | localDst (8 bits) << 24.
__global__ __launch_bounds__(256)
void binA(const int* __restrict__ hs0, const int* __restrict__ hd0,
          const int* __restrict__ ss0, const int* __restrict__ sd0,
          const int* __restrict__ hs1, const int* __restrict__ hd1,
          const int* __restrict__ ss1, const int* __restrict__ sd1,
          int EH, int ES, int* __restrict__ bcur, unsigned* __restrict__ recs,
          int nb2) {
    int y = blockIdx.y;
    const int* src = (y == 0) ? hs0 : (y == 1) ? ss0 : (y == 2) ? hs1 : ss1;
    const int* dst = (y == 0) ? hd0 : (y == 1) ? sd0 : (y == 2) ? hd1 : sd1;
    int E = (y & 1) ? ES : EH;
    unsigned* rb = recs + yoff(y, EH, ES);

    __shared__ int cnt[256];
    int t = threadIdx.x;
    cnt[t] = 0;
    __syncthreads();
    int i0 = blockIdx.x * EPB;
    #pragma unroll
    for (int j = 0; j < 16; ++j) {
        int i = i0 + j * 256 + t;
        if (i < E) atomicAdd(&cnt[dst[i] >> 8], 1);
    }
    __syncthreads();
    int c = cnt[t];
    __syncthreads();
    if (t < nb2 && c > 0) cnt[t] = atomicAdd(&bcur[y * nb2 + t], c);
    __syncthreads();
    #pragma unroll
    for (int j = 0; j < 16; ++j) {
        int i = i0 + j * 256 + t;
        if (i < E) {
            int dd = dst[i];
            int slot = atomicAdd(&cnt[dd >> 8], 1);
            rb[slot] = (unsigned)src[i] | ((unsigned)(dd & 255) << 24);
        }
    }
}

__global__ __launch_bounds__(256)
void placeB(const unsigned* __restrict__ recs, const int* __restrict__ rpBucket,
            int* __restrict__ rpAll, int* __restrict__ srcAll,
            int EH, int ES, int n, int nb2) {
    int y = blockIdx.y;
    int b = blockIdx.x;
    int E = (y & 1) ? ES : EH;
    int* rp = rpAll + (size_t)y * (n + 1);
    long off = yoff(y, EH, ES);
    const unsigned* rb = recs + off;
    int* sb = srcAll + off;
    int e0 = rpBucket[y * (nb2 + 1) + b];
    int e1 = rpBucket[y * (nb2 + 1) + b + 1];
    int nodeBase = b << 8;

    __shared__ int cnt[256];
    __shared__ int sh[256];
    int t = threadIdx.x;
    cnt[t] = 0;
    __syncthreads();
    for (int e = e0 + t; e < e1; e += 256)
        atomicAdd(&cnt[rb[e] >> 24], 1);
    __syncthreads();
    sh[t] = cnt[t];
    __syncthreads();
    for (int o = 1; o < 256; o <<= 1) {
        int x = (t >= o) ? sh[t - o] : 0;
        __syncthreads();
        sh[t] += x;
        __syncthreads();
    }
    int base = e0 + (t ? sh[t - 1] : 0);
    if (nodeBase + t < n) rp[nodeBase + t] = base;
    if (b == 0 && t == 0) rp[n] = E;
    cnt[t] = base;
    __syncthreads();
    for (int e = e0 + t; e < e1; e += 256) {
        unsigned r = rb[e];
        int p = atomicAdd(&cnt[r >> 24], 1);
        sb[p] = (int)(r & 0x00FFFFFFu);
    }
}

// ---------------- upfront bf16 prep ----------------
__global__ __launch_bounds__(256)
void prep_static(const float4* __restrict__ x, const float4* __restrict__ hbar0,
                 const float4* __restrict__ hbar1,
                 uint4* __restrict__ hb0, uint4* __restrict__ db0,
                 uint4* __restrict__ hb1, uint4* __restrict__ z, int n16) {
    int i = blockIdx.x * 256 + threadIdx.x;
    if (i >= n16) return;
    float4 xa = x[i * 2],     xb = x[i * 2 + 1];
    float4 ba = hbar0[i * 2], bb = hbar0[i * 2 + 1];
    float4 ca = hbar1[i * 2], cb = hbar1[i * 2 + 1];
    hb0[i] = pack8(ba, bb);
    db0[i] = pack8(make_float4(xa.x - ba.x, xa.y - ba.y, xa.z - ba.z, xa.w - ba.w),
                   make_float4(xb.x - bb.x, xb.y - bb.y, xb.z - bb.z, xb.w - bb.w));
    hb1[i] = pack8(ca, cb);
    int g = i >> 4, seg = i & 15;
    z[(size_t)g * 32 + seg] = pack8(xa, xb);   // z left half = bf16(x row)
}

__global__ __launch_bounds__(256)
void conv_weights(const float* __restrict__ W0, unsigned short* __restrict__ Wb0,
                  const float* __restrict__ W1, unsigned short* __restrict__ Wb1) {
    int i = blockIdx.x * 256 + threadIdx.x;
    if (i < 128 * 256) Wb0[i] = f2b(W0[i]);
    if (i < 64 * 256) {
        int r = i >> 8;
        Wb1[i] = (r < 47) ? f2b(W1[i]) : (unsigned short)0;
    }
}

// ---------------- aggregation: one full wave per node ----------------
__global__ __launch_bounds__(256)
void aggregate_z(const uint4* __restrict__ HB, const uint4* __restrict__ DB,
                 const int* __restrict__ rpH, const int* __restrict__ srcH,
                 const int* __restrict__ rpS, const int* __restrict__ srcS,
                 uint4* __restrict__ z, int n) {
    int g = blockIdx.x * 4 + (threadIdx.x >> 6);
    if (g >= n) return;
    int lane = threadIdx.x & 63;
    int j = lane >> 4, l = lane & 15;

    int hb_ = rpH[g], he = rpH[g + 1];
    int sb  = rpS[g], se = rpS[g + 1];

    float a[8] = {0, 0, 0, 0, 0, 0, 0, 0};
    for (int e0 = hb_; e0 < he; e0 += 8) {
        int e1 = e0 + j, e2 = e0 + 4 + j;
        uint4 v1 = make_uint4(0, 0, 0, 0), v2 = make_uint4(0, 0, 0, 0);
        if (e1 < he) v1 = HB[(size_t)srcH[e1] * 16 + l];
        if (e2 < he) v2 = HB[(size_t)srcH[e2] * 16 + l];
        addu4(a, v1); addu4(a, v2);
    }
    float d[8] = {0, 0, 0, 0, 0, 0, 0, 0};
    for (int e0 = sb; e0 < se; e0 += 8) {
        int e1 = e0 + j, e2 = e0 + 4 + j;
        uint4 v1 = make_uint4(0, 0, 0, 0), v2 = make_uint4(0, 0, 0, 0);
        if (e1 < se) v1 = DB[(size_t)srcS[e1] * 16 + l];
        if (e2 < se) v2 = DB[(size_t)srcS[e2] * 16 + l];
        addu4(d, v1); addu4(d, v2);
    }

    float rH = 1.0f / fmaxf((float)(he - hb_), 1.0f);
    float rS = 1.0f / fmaxf((float)(se - sb), 1.0f);
    float s[8];
    #pragma unroll
    for (int i = 0; i < 8; ++i) {
        float v = a[i] * rH + d[i] * rS;
        v += __shfl_xor(v, 16);
        v += __shfl_xor(v, 32);
        s[i] = v;
    }
    if (j == 0) {
        uint4 rv = make_uint4(pack2(s[0], s[1]), pack2(s[2], s[3]),
                              pack2(s[4], s[5]), pack2(s[6], s[7]));
        z[(size_t)g * 32 + 16 + l] = rv;   // right half: h_neigh
    }
}

// ---------------- MFMA GEMM layer 0: fused epilogue (LDS-transposed) ----------------
// Block: 256 thr = 4 waves; 32 rows/block. Wave (rt,ch): rows rt*16..+16, cols ch*64..+64.
// Epilogue stages relu(acc+bias) as bf16 in LDS, then coalesced uint4/float4 write-out.
__global__ __launch_bounds__(256)
void gemm_mfma_l0(const unsigned short* __restrict__ Z, const unsigned short* __restrict__ Wb,
                  const float* __restrict__ bias, const float* __restrict__ hbar1,
                  unsigned short* __restrict__ db1, unsigned short* __restrict__ zl, int n) {
    __shared__ unsigned short hl[32 * PADL];
    int tid  = threadIdx.x;
    int wave = tid >> 6;
    int lane = tid & 63;
    int rt = wave >> 1;                 // row tile 0..1
    int ch = wave & 1;                  // col half 0..1
    int m0 = blockIdx.x * 32;
    int cl = lane & 15;
    int kq = lane >> 4;

    int mr = m0 + rt * 16 + cl;
    int mc = (mr < n) ? mr : (n - 1);

    const short* Zs = (const short*)Z;
    const short* Ws = (const short*)Wb;
    const short* aP = Zs + (size_t)mc * 256 + kq * 8;
    const short* bP = Ws + (size_t)(ch * 64 + cl) * 256 + kq * 8;

    f32x4 acc[4] = {};
    bf16x8 aF[2];
    bf16x8 bF[2][4];
    aF[0] = *(const bf16x8*)(aP);
    #pragma unroll
    for (int t = 0; t < 4; ++t) bF[0][t] = *(const bf16x8*)(bP + t * 16 * 256);

    #pragma unroll
    for (int k0 = 0; k0 < 8; ++k0) {
        int cur = k0 & 1, nxt = cur ^ 1;
        if (k0 < 7) {
            int ko = (k0 + 1) * 32;
            aF[nxt] = *(const bf16x8*)(aP + ko);
            #pragma unroll
            for (int t = 0; t < 4; ++t)
                bF[nxt][t] = *(const bf16x8*)(bP + t * 16 * 256 + ko);
        }
        #pragma unroll
        for (int t = 0; t < 4; ++t)
            acc[t] = __builtin_amdgcn_mfma_f32_16x16x32_bf16(aF[cur], bF[cur][t], acc[t], 0, 0, 0);
    }

    // stage h = relu(acc + bias) into LDS tile [32][PADL] (bf16)
    #pragma unroll
    for (int t = 0; t < 4; ++t) {
        int c = ch * 64 + t * 16 + cl;
        float bv = bias[c];
        #pragma unroll
        for (int r = 0; r < 4; ++r) {
            int row = rt * 16 + kq * 4 + r;
            hl[row * PADL + c] = f2b(fmaxf(acc[t][r] + bv, 0.0f));
        }
    }
    __syncthreads();

    // coalesced write-out: thread -> (row = tid/8, 16 cols at (tid%8)*16)
    int row  = tid >> 3;
    int col  = (tid & 7) * 16;
    int m    = m0 + row;
    if (m < n) {
        const uint4* hr = (const uint4*)(hl + row * PADL + col);
        uint4 v0 = hr[0];              // cols col..col+7
        uint4 v1 = hr[1];              // cols col+8..col+15
        // zl: h as bf16, straight copy
        uint4* zp = (uint4*)(zl + (size_t)m * 256 + col);
        zp[0] = v0;
        zp[1] = v1;
        // db1 = bf16(h - hbar1), hbar1 read coalesced as float4
        const float4* hb = (const float4*)(hbar1 + (size_t)m * 128 + col);
        float4 h0 = hb[0], h1 = hb[1], h2 = hb[2], h3 = hb[3];
        uint4 d0, d1;
        d0.x = pack2(blo(v0.x) - h0.x, bhi(v0.x) - h0.y);
        d0.y = pack2(blo(v0.y) - h0.z, bhi(v0.y) - h0.w);
        d0.z = pack2(blo(v0.z) - h1.x, bhi(v0.z) - h1.y);
        d0.w = pack2(blo(v0.w) - h1.z, bhi(v0.w) - h1.w);
        d1.x = pack2(blo(v1.x) - h2.x, bhi(v1.x) - h2.y);
        d1.y = pack2(blo(v1.y) - h2.z, bhi(v1.y) - h2.w);
        d1.z = pack2(blo(v1.z) - h3.x, bhi(v1.z) - h3.y);
        d1.w = pack2(blo(v1.w) - h3.z, bhi(v1.w) - h3.w);
        uint4* dp = (uint4*)(db1 + (size_t)m * 128 + col);
        dp[0] = d0;
        dp[1] = d1;
    }
}

// ---------------- MFMA GEMM layer 1 -> f32 out ----------------
// 128-thread blocks (2 waves, 32 rows) + double-buffered fragment prefetch.
template<int NT>
__global__ __launch_bounds__(128)
void gemm_mfma(const unsigned short* __restrict__ Z, const unsigned short* __restrict__ Wb,
               const float* __restrict__ bias, float* __restrict__ out, int n, int COLS) {
    int wave = threadIdx.x >> 6;
    int lane = threadIdx.x & 63;
    int m0 = blockIdx.x * 32 + wave * 16;
    int mr = m0 + (lane & 15);
    int mc = (mr < n) ? mr : (n - 1);
    int kq = lane >> 4;
    int cl = lane & 15;

    const short* Zs = (const short*)Z;
    const short* Ws = (const short*)Wb;
    const short* aP = Zs + (size_t)mc * 256 + kq * 8;
    const short* bP = Ws + (size_t)cl * 256 + kq * 8;

    f32x4 acc[NT] = {};
    bf16x8 aF[2];
    bf16x8 bF[2][NT];
    aF[0] = *(const bf16x8*)(aP);
    #pragma unroll
    for (int t = 0; t < NT; ++t) bF[0][t] = *(const bf16x8*)(bP + t * 16 * 256);

    #pragma unroll
    for (int k0 = 0; k0 < 8; ++k0) {
        int cur = k0 & 1, nxt = cur ^ 1;
        if (k0 < 7) {
            int ko = (k0 + 1) * 32;
            aF[nxt] = *(const bf16x8*)(aP + ko);
            #pragma unroll
            for (int t = 0; t < NT; ++t)
                bF[nxt][t] = *(const bf16x8*)(bP + t * 16 * 256 + ko);
        }
        #pragma unroll
        for (int t = 0; t < NT; ++t)
            acc[t] = __builtin_amdgcn_mfma_f32_16x16x32_bf16(aF[cur], bF[cur][t], acc[t], 0, 0, 0);
    }

    int rg = kq * 4;
    #pragma unroll
    for (int t = 0; t < NT; ++t) {
        int c = t * 16 + cl;
        if (c >= COLS) continue;
        float bv = bias[c];
        #pragma unroll
        for (int r = 0; r < 4; ++r) {
            int m = m0 + rg + r;
            if (m < n) out[(size_t)m * COLS + c] = fmaxf(acc[t][r] + bv, 0.f);
        }
    }
}

extern "C" void kernel_launch(void* const* d_in, const int* in_sizes, int n_in,
                              void* d_out, int out_size, void* d_ws, size_t ws_size,
                              hipStream_t stream) {
    const float* x     = (const float*)d_in[0];
    const float* hbar0 = (const float*)d_in[1];
    const float* hbar1 = (const float*)d_in[2];
    const float* W0    = (const float*)d_in[3];
    const float* b0    = (const float*)d_in[4];
    const float* W1    = (const float*)d_in[5];
    const float* b1    = (const float*)d_in[6];
    const int* hs0 = (const int*)d_in[7];
    const int* hd0 = (const int*)d_in[8];
    const int* ss0 = (const int*)d_in[9];
    const int* sd0 = (const int*)d_in[10];
    const int* hs1 = (const int*)d_in[11];
    const int* hd1 = (const int*)d_in[12];
    const int* ss1 = (const int*)d_in[13];
    const int* sd1 = (const int*)d_in[14];

    const int n   = in_sizes[0] / D_FEAT;   // 50000
    const int EH  = in_sizes[7];            // 500000
    const int ES  = in_sizes[9];            // 250000
    const int nb2 = (n + 255) / 256;        // 196 dst buckets per etype

    // ---- workspace layout ----
    int* bucketCnt = (int*)d_ws;                       // 4*nb2
    int* rpBucket  = bucketCnt + 4 * nb2;              // 4*(nb2+1)
    int* bcur      = rpBucket + 4 * (nb2 + 1);         // 4*nb2
    int* rpAll     = bcur + 4 * nb2;                   // 4*(n+1)
    int* srcAll    = rpAll + 4 * (size_t)(n + 1);      // 2EH+2ES
    unsigned* recs = (unsigned*)(srcAll + 2 * (size_t)EH + 2 * (size_t)ES); // 2EH+2ES
    size_t int_words = (size_t)12 * nb2 + 4 + 4 * (size_t)(n + 1)
                     + 4 * (size_t)EH + 4 * (size_t)ES;
    int_words = (int_words + 3) & ~(size_t)3;                          // 16 B align
    unsigned short* hb0 = (unsigned short*)((int*)d_ws + int_words);   // n*128 bf16
    unsigned short* db0 = hb0 + (size_t)n * D_FEAT;                    // n*128 bf16
    unsigned short* hb1 = db0 + (size_t)n * D_FEAT;                    // n*128 bf16
    unsigned short* db1 = hb1 + (size_t)n * D_FEAT;                    // n*128 bf16
    unsigned short* z   = db1 + (size_t)n * D_FEAT;                    // n*256 bf16
    unsigned short* Wb0 = z + (size_t)n * K_DIM;                       // 128*256
    unsigned short* Wb1 = Wb0 + 128 * 256;                             // 64*256

    const int* rpH0 = rpAll;
    const int* rpS0 = rpAll + (size_t)(n + 1);
    const int* rpH1 = rpAll + 2 * (size_t)(n + 1);
    const int* rpS1 = rpAll + 3 * (size_t)(n + 1);
    int* srcH0 = srcAll;
    int* srcS0 = srcAll + (size_t)EH;
    int* srcH1 = srcAll + (size_t)EH + ES;
    int* srcS1 = srcAll + 2 * (size_t)EH + ES;

    dim3 blk(256);
    int binb  = (EH + EPB - 1) / EPB;
    int prepb = ((n * 16) + 255) / 256;
    int aggb  = (n + 3) / 4;
    int gemmb0 = (n + 31) / 32;   // 32 rows per block (layer-0 GEMM)
    int gemmb1 = (n + 31) / 32;   // 32 rows per block (layer-1 GEMM, 128 thr)

    // ---- CSR build for BOTH layers + static prep ----
    hipMemsetAsync(bucketCnt, 0, 4 * (size_t)nb2 * sizeof(int), stream);
    conv_weights<<<128, blk, 0, stream>>>(W0, Wb0, W1, Wb1);
    histB<<<dim3(binb, 4), blk, 0, stream>>>(hd0, sd0, hd1, sd1, EH, ES, bucketCnt, nb2);
    scanBuckets<<<1, 64, 0, stream>>>(bucketCnt, rpBucket, bcur, nb2);
    binA<<<dim3(binb, 4), blk, 0, stream>>>(hs0, hd0, ss0, sd0, hs1, hd1, ss1, sd1,
                                            EH, ES, bcur, recs, nb2);
    placeB<<<dim3(nb2, 4), blk, 0, stream>>>(recs, rpBucket, rpAll, srcAll, EH, ES, n, nb2);
    prep_static<<<prepb, blk, 0, stream>>>((const float4*)x, (const float4*)hbar0,
                                           (const float4*)hbar1, (uint4*)hb0, (uint4*)db0,
                                           (uint4*)hb1, (uint4*)z, n * 16);

    // ---------------- Layer 0 ----------------
    aggregate_z<<<aggb, blk, 0, stream>>>((const uint4*)hb0, (const uint4*)db0,
                                          rpH0, srcH0, rpS0, srcS0, (uint4*)z, n);
    gemm_mfma_l0<<<gemmb0, blk, 0, stream>>>(z, Wb0, b0, hbar1, db1, z, n);

    // ---------------- Layer 1 ----------------
    aggregate_z<<<aggb, blk, 0, stream>>>((const uint4*)hb1, (const uint4*)db1,
                                          rpH1, srcH1, rpS1, srcS1, (uint4*)z, n);
    gemm_mfma<3><<<gemmb1, dim3(128), 0, stream>>>(z, Wb1, b1, (float*)d_out, n, 47);
}

// Round 2
// 331.707 us; speedup vs baseline: 1.0383x; 1.0292x over previous
//
#include <hip/hip_runtime.h>

// N=50000, D=128 (both layers), K=256, EH=500000, ES=250000.
#define D_FEAT 128
#define K_DIM  256
#define EPB 4096
#define PADL 136   // LDS leading dim (ushorts) for the 32x128 epilogue tile; 272B row, 16B-aligned

typedef __attribute__((ext_vector_type(8))) short bf16x8;
typedef __attribute__((ext_vector_type(4))) float f32x4;

__device__ __forceinline__ unsigned short f2b(float f) {
    union { float f; unsigned u; } cv; cv.f = f;
    return (unsigned short)((cv.u + 0x7fffu + ((cv.u >> 16) & 1u)) >> 16);
}

__device__ __forceinline__ unsigned pack2(float lo, float hi) {
    return (unsigned)f2b(lo) | ((unsigned)f2b(hi) << 16);
}

__device__ __forceinline__ uint4 pack8(float4 a, float4 b) {
    return make_uint4(pack2(a.x, a.y), pack2(a.z, a.w), pack2(b.x, b.y), pack2(b.z, b.w));
}

// unpack uint4 = 8 bf16 (low half of word = even element) and accumulate
__device__ __forceinline__ void addu4(float* a, uint4 v) {
    union { unsigned u; float f; } c;
    c.u = v.x << 16;         a[0] += c.f;
    c.u = v.x & 0xffff0000u; a[1] += c.f;
    c.u = v.y << 16;         a[2] += c.f;
    c.u = v.y & 0xffff0000u; a[3] += c.f;
    c.u = v.z << 16;         a[4] += c.f;
    c.u = v.z & 0xffff0000u; a[5] += c.f;
    c.u = v.w << 16;         a[6] += c.f;
    c.u = v.w & 0xffff0000u; a[7] += c.f;
}

__device__ __forceinline__ float blo(unsigned u) { union { unsigned u; float f; } c; c.u = u << 16; return c.f; }
__device__ __forceinline__ float bhi(unsigned u) { union { unsigned u; float f; } c; c.u = u & 0xffff0000u; return c.f; }

// edge-array offset within the concatenated [H0|S0|H1|S1] space
__device__ __forceinline__ long yoff(int y, int EH, int ES) {
    return (long)((y + 1) >> 1) * EH + (long)(y >> 1) * ES;
}

// ---------------- bucket-level CSR build (both layers; y in 0..3) ----------------

__global__ __launch_bounds__(256)
void histB(const int* __restrict__ hd0, const int* __restrict__ sd0,
           const int* __restrict__ hd1, const int* __restrict__ sd1,
           int EH, int ES, int* __restrict__ bucketCnt, int nb2) {
    int y = blockIdx.y;
    const int* d = (y == 0) ? hd0 : (y == 1) ? sd0 : (y == 2) ? hd1 : sd1;
    int E = (y & 1) ? ES : EH;
    __shared__ int cnt[256];
    int t = threadIdx.x;
    cnt[t] = 0;
    __syncthreads();
    int i0 = blockIdx.x * EPB;
    #pragma unroll
    for (int j = 0; j < 16; ++j) {
        int i = i0 + j * 256 + t;
        if (i < E) atomicAdd(&cnt[d[i] >> 8], 1);
    }
    __syncthreads();
    if (t < nb2 && cnt[t] > 0) atomicAdd(&bucketCnt[y * nb2 + t], cnt[t]);
}

// Parallel exclusive scan of the 196 bucket counts per etype (one block per etype).
__global__ __launch_bounds__(256)
void scanBuckets(const int* __restrict__ bucketCnt, int* __restrict__ rpBucket,
                 int* __restrict__ bcur, int nb2) {
    int y = blockIdx.x;
    int t = threadIdx.x;
    __shared__ int sh[256];
    int c = (t < nb2) ? bucketCnt[y * nb2 + t] : 0;
    sh[t] = c;
    __syncthreads();
    for (int o = 1; o < 256; o <<= 1) {
        int x = (t >= o) ? sh[t - o] : 0;
        __syncthreads();
        sh[t] += x;
        __syncthreads();
    }
    int excl = t ? sh[t - 1] : 0;
    if (t < nb2) {
        rpBucket[y * (nb2 + 1) + t] = excl;
        bcur[y * nb2 + t] = excl;
    }
    if (t == 0) rpBucket[y * (nb2 + 1) + nb2] = sh[255];  // total = E
}

// Record: src (24 bits) | localDst (8 bits) << 24.
__global__ __launch_bounds__(256)
void binA(const int* __restrict__ hs0, const int* __restrict__ hd0,
          const int* __restrict__ ss0, const int* __restrict__ sd0,
          const int* __restrict__ hs1, const int* __restrict__ hd1,
          const int* __restrict__ ss1, const int* __restrict__ sd1,
          int EH, int ES, int* __restrict__ bcur, unsigned* __restrict__ recs,
          int nb2) {
    int y = blockIdx.y;
    const int* src = (y == 0) ? hs0 : (y == 1) ? ss0 : (y == 2) ? hs1 : ss1;
    const int* dst = (y == 0) ? hd0 : (y == 1) ? sd0 : (y == 2) ? hd1 : sd1;
    int E = (y & 1) ? ES : EH;
    unsigned* rb = recs + yoff(y, EH, ES);

    __shared__ int cnt[256];
    int t = threadIdx.x;
    cnt[t] = 0;
    __syncthreads();
    int i0 = blockIdx.x * EPB;
    #pragma unroll
    for (int j = 0; j < 16; ++j) {
        int i = i0 + j * 256 + t;
        if (i < E) atomicAdd(&cnt[dst[i] >> 8], 1);
    }
    __syncthreads();
    int c = cnt[t];
    __syncthreads();
    if (t < nb2 && c > 0) cnt[t] = atomicAdd(&bcur[y * nb2 + t], c);
    __syncthreads();
    #pragma unroll
    for (int j = 0; j < 16; ++j) {
        int i = i0 + j * 256 + t;
        if (i < E) {
            int dd = dst[i];
            int slot = atomicAdd(&cnt[dd >> 8], 1);
            rb[slot] = (unsigned)src[i] | ((unsigned)(dd & 255) << 24);
        }
    }
}

__global__ __launch_bounds__(256)
void placeB(const unsigned* __restrict__ recs, const int* __restrict__ rpBucket,
            int* __restrict__ rpAll, int* __restrict__ srcAll,
            int EH, int ES, int n, int nb2) {
    int y = blockIdx.y;
    int b = blockIdx.x;
    int E = (y & 1) ? ES : EH;
    int* rp = rpAll + (size_t)y * (n + 1);
    long off = yoff(y, EH, ES);
    const unsigned* rb = recs + off;
    int* sb = srcAll + off;
    int e0 = rpBucket[y * (nb2 + 1) + b];
    int e1 = rpBucket[y * (nb2 + 1) + b + 1];
    int nodeBase = b << 8;

    __shared__ int cnt[256];
    __shared__ int sh[256];
    int t = threadIdx.x;
    cnt[t] = 0;
    __syncthreads();
    for (int e = e0 + t; e < e1; e += 256)
        atomicAdd(&cnt[rb[e] >> 24], 1);
    __syncthreads();
    sh[t] = cnt[t];
    __syncthreads();
    for (int o = 1; o < 256; o <<= 1) {
        int x = (t >= o) ? sh[t - o] : 0;
        __syncthreads();
        sh[t] += x;
        __syncthreads();
    }
    int base = e0 + (t ? sh[t - 1] : 0);
    if (nodeBase + t < n) rp[nodeBase + t] = base;
    if (b == 0 && t == 0) rp[n] = E;
    cnt[t] = base;
    __syncthreads();
    for (int e = e0 + t; e < e1; e += 256) {
        unsigned r = rb[e];
        int p = atomicAdd(&cnt[r >> 24], 1);
        sb[p] = (int)(r & 0x00FFFFFFu);
    }
}

// ---------------- upfront bf16 prep ----------------
__global__ __launch_bounds__(256)
void prep_static(const float4* __restrict__ x, const float4* __restrict__ hbar0,
                 const float4* __restrict__ hbar1,
                 uint4* __restrict__ hb0, uint4* __restrict__ db0,
                 uint4* __restrict__ hb1, uint4* __restrict__ z, int n16) {
    int i = blockIdx.x * 256 + threadIdx.x;
    if (i >= n16) return;
    float4 xa = x[i * 2],     xb = x[i * 2 + 1];
    float4 ba = hbar0[i * 2], bb = hbar0[i * 2 + 1];
    float4 ca = hbar1[i * 2], cb = hbar1[i * 2 + 1];
    hb0[i] = pack8(ba, bb);
    db0[i] = pack8(make_float4(xa.x - ba.x, xa.y - ba.y, xa.z - ba.z, xa.w - ba.w),
                   make_float4(xb.x - bb.x, xb.y - bb.y, xb.z - bb.z, xb.w - bb.w));
    hb1[i] = pack8(ca, cb);
    int g = i >> 4, seg = i & 15;
    z[(size_t)g * 32 + seg] = pack8(xa, xb);   // z left half = bf16(x row)
}

__global__ __launch_bounds__(256)
void conv_weights(const float* __restrict__ W0, unsigned short* __restrict__ Wb0,
                  const float* __restrict__ W1, unsigned short* __restrict__ Wb1) {
    int i = blockIdx.x * 256 + threadIdx.x;
    if (i < 128 * 256) Wb0[i] = f2b(W0[i]);
    if (i < 64 * 256) {
        int r = i >> 8;
        Wb1[i] = (r < 47) ? f2b(W1[i]) : (unsigned short)0;
    }
}

// ---------------- aggregation: one full wave per node ----------------
__global__ __launch_bounds__(256)
void aggregate_z(const uint4* __restrict__ HB, const uint4* __restrict__ DB,
                 const int* __restrict__ rpH, const int* __restrict__ srcH,
                 const int* __restrict__ rpS, const int* __restrict__ srcS,
                 uint4* __restrict__ z, int n) {
    int g = blockIdx.x * 4 + (threadIdx.x >> 6);
    if (g >= n) return;
    int lane = threadIdx.x & 63;
    int j = lane >> 4, l = lane & 15;

    int hb_ = rpH[g], he = rpH[g + 1];
    int sb  = rpS[g], se = rpS[g + 1];

    float a[8] = {0, 0, 0, 0, 0, 0, 0, 0};
    for (int e0 = hb_; e0 < he; e0 += 8) {
        int e1 = e0 + j, e2 = e0 + 4 + j;
        uint4 v1 = make_uint4(0, 0, 0, 0), v2 = make_uint4(0, 0, 0, 0);
        if (e1 < he) v1 = HB[(size_t)srcH[e1] * 16 + l];
        if (e2 < he) v2 = HB[(size_t)srcH[e2] * 16 + l];
        addu4(a, v1); addu4(a, v2);
    }
    float d[8] = {0, 0, 0, 0, 0, 0, 0, 0};
    for (int e0 = sb; e0 < se; e0 += 8) {
        int e1 = e0 + j, e2 = e0 + 4 + j;
        uint4 v1 = make_uint4(0, 0, 0, 0), v2 = make_uint4(0, 0, 0, 0);
        if (e1 < se) v1 = DB[(size_t)srcS[e1] * 16 + l];
        if (e2 < se) v2 = DB[(size_t)srcS[e2] * 16 + l];
        addu4(d, v1); addu4(d, v2);
    }

    float rH = 1.0f / fmaxf((float)(he - hb_), 1.0f);
    float rS = 1.0f / fmaxf((float)(se - sb), 1.0f);
    float s[8];
    #pragma unroll
    for (int i = 0; i < 8; ++i) {
        float v = a[i] * rH + d[i] * rS;
        v += __shfl_xor(v, 16);
        v += __shfl_xor(v, 32);
        s[i] = v;
    }
    if (j == 0) {
        uint4 rv = make_uint4(pack2(s[0], s[1]), pack2(s[2], s[3]),
                              pack2(s[4], s[5]), pack2(s[6], s[7]));
        z[(size_t)g * 32 + 16 + l] = rv;   // right half: h_neigh
    }
}

// ---------------- MFMA GEMM layer 0: fused epilogue (LDS-transposed) ----------------
// Block: 256 thr = 4 waves; 32 rows/block. Wave (rt,ch): rows rt*16..+16, cols ch*64..+64.
// A row-slice (K=256) loaded fully upfront -> 8 loads in flight; B 1-step double-buffer.
// __launch_bounds__(256,2): min 2 waves/EU -> 256-VGPR budget so prefetch regs survive.
__global__ __launch_bounds__(256, 2)
void gemm_mfma_l0(const unsigned short* __restrict__ Z, const unsigned short* __restrict__ Wb,
                  const float* __restrict__ bias, const float* __restrict__ hbar1,
                  unsigned short* __restrict__ db1, unsigned short* __restrict__ zl, int n) {
    __shared__ unsigned short hl[32 * PADL];
    int tid  = threadIdx.x;
    int wave = tid >> 6;
    int lane = tid & 63;
    int rt = wave >> 1;                 // row tile 0..1
    int ch = wave & 1;                  // col half 0..1
    int m0 = blockIdx.x * 32;
    int cl = lane & 15;
    int kq = lane >> 4;

    int mr = m0 + rt * 16 + cl;
    int mc = (mr < n) ? mr : (n - 1);

    const short* Zs = (const short*)Z;
    const short* Ws = (const short*)Wb;
    const short* aP = Zs + (size_t)mc * 256 + kq * 8;
    const short* bP = Ws + (size_t)(ch * 64 + cl) * 256 + kq * 8;

    // entire A row-slice upfront: 8 independent loads (32 VGPR)
    bf16x8 aF[8];
    #pragma unroll
    for (int k0 = 0; k0 < 8; ++k0) aF[k0] = *(const bf16x8*)(aP + k0 * 32);

    f32x4 acc[4] = {};
    bf16x8 bF[2][4];
    #pragma unroll
    for (int t = 0; t < 4; ++t) bF[0][t] = *(const bf16x8*)(bP + t * 16 * 256);

    #pragma unroll
    for (int k0 = 0; k0 < 8; ++k0) {
        int cur = k0 & 1, nxt = cur ^ 1;
        if (k0 < 7) {
            int ko = (k0 + 1) * 32;
            #pragma unroll
            for (int t = 0; t < 4; ++t)
                bF[nxt][t] = *(const bf16x8*)(bP + t * 16 * 256 + ko);
        }
        #pragma unroll
        for (int t = 0; t < 4; ++t)
            acc[t] = __builtin_amdgcn_mfma_f32_16x16x32_bf16(aF[k0], bF[cur][t], acc[t], 0, 0, 0);
    }

    // stage h = relu(acc + bias) into LDS tile [32][PADL] (bf16)
    #pragma unroll
    for (int t = 0; t < 4; ++t) {
        int c = ch * 64 + t * 16 + cl;
        float bv = bias[c];
        #pragma unroll
        for (int r = 0; r < 4; ++r) {
            int row = rt * 16 + kq * 4 + r;
            hl[row * PADL + c] = f2b(fmaxf(acc[t][r] + bv, 0.0f));
        }
    }
    __syncthreads();

    // coalesced write-out: thread -> (row = tid/8, 16 cols at (tid%8)*16)
    int row  = tid >> 3;
    int col  = (tid & 7) * 16;
    int m    = m0 + row;
    if (m < n) {
        const uint4* hr = (const uint4*)(hl + row * PADL + col);
        uint4 v0 = hr[0];              // cols col..col+7
        uint4 v1 = hr[1];              // cols col+8..col+15
        // zl: h as bf16, straight copy
        uint4* zp = (uint4*)(zl + (size_t)m * 256 + col);
        zp[0] = v0;
        zp[1] = v1;
        // db1 = bf16(h - hbar1), hbar1 read coalesced as float4
        const float4* hb = (const float4*)(hbar1 + (size_t)m * 128 + col);
        float4 h0 = hb[0], h1 = hb[1], h2 = hb[2], h3 = hb[3];
        uint4 d0, d1;
        d0.x = pack2(blo(v0.x) - h0.x, bhi(v0.x) - h0.y);
        d0.y = pack2(blo(v0.y) - h0.z, bhi(v0.y) - h0.w);
        d0.z = pack2(blo(v0.z) - h1.x, bhi(v0.z) - h1.y);
        d0.w = pack2(blo(v0.w) - h1.z, bhi(v0.w) - h1.w);
        d1.x = pack2(blo(v1.x) - h2.x, bhi(v1.x) - h2.y);
        d1.y = pack2(blo(v1.y) - h2.z, bhi(v1.y) - h2.w);
        d1.z = pack2(blo(v1.z) - h3.x, bhi(v1.z) - h3.y);
        d1.w = pack2(blo(v1.w) - h3.z, bhi(v1.w) - h3.w);
        uint4* dp = (uint4*)(db1 + (size_t)m * 128 + col);
        dp[0] = d0;
        dp[1] = d1;
    }
}

// ---------------- MFMA GEMM layer 1 -> f32 out ----------------
// 128-thread blocks (2 waves, 32 rows); A row-slice fully upfront; B double-buffered.
template<int NT>
__global__ __launch_bounds__(128, 2)
void gemm_mfma(const unsigned short* __restrict__ Z, const unsigned short* __restrict__ Wb,
               const float* __restrict__ bias, float* __restrict__ out, int n, int COLS) {
    int wave = threadIdx.x >> 6;
    int lane = threadIdx.x & 63;
    int m0 = blockIdx.x * 32 + wave * 16;
    int cl = lane & 15;
    int kq = lane >> 4;
    int mr = m0 + cl;
    int mc = (mr < n) ? mr : (n - 1);

    const short* Zs = (const short*)Z;
    const short* Ws = (const short*)Wb;
    const short* aP = Zs + (size_t)mc * 256 + kq * 8;
    const short* bP = Ws + (size_t)cl * 256 + kq * 8;

    bf16x8 aF[8];
    #pragma unroll
    for (int k0 = 0; k0 < 8; ++k0) aF[k0] = *(const bf16x8*)(aP + k0 * 32);

    f32x4 acc[NT] = {};
    bf16x8 bF[2][NT];
    #pragma unroll
    for (int t = 0; t < NT; ++t) bF[0][t] = *(const bf16x8*)(bP + t * 16 * 256);

    #pragma unroll
    for (int k0 = 0; k0 < 8; ++k0) {
        int cur = k0 & 1, nxt = cur ^ 1;
        if (k0 < 7) {
            int ko = (k0 + 1) * 32;
            #pragma unroll
            for (int t = 0; t < NT; ++t)
                bF[nxt][t] = *(const bf16x8*)(bP + t * 16 * 256 + ko);
        }
        #pragma unroll
        for (int t = 0; t < NT; ++t)
            acc[t] = __builtin_amdgcn_mfma_f32_16x16x32_bf16(aF[k0], bF[cur][t], acc[t], 0, 0, 0);
    }

    int rg = kq * 4;
    #pragma unroll
    for (int t = 0; t < NT; ++t) {
        int c = t * 16 + cl;
        if (c >= COLS) continue;
        float bv = bias[c];
        #pragma unroll
        for (int r = 0; r < 4; ++r) {
            int m = m0 + rg + r;
            if (m < n) out[(size_t)m * COLS + c] = fmaxf(acc[t][r] + bv, 0.f);
        }
    }
}

extern "C" void kernel_launch(void* const* d_in, const int* in_sizes, int n_in,
                              void* d_out, int out_size, void* d_ws, size_t ws_size,
                              hipStream_t stream) {
    const float* x     = (const float*)d_in[0];
    const float* hbar0 = (const float*)d_in[1];
    const float* hbar1 = (const float*)d_in[2];
    const float* W0    = (const float*)d_in[3];
    const float* b0    = (const float*)d_in[4];
    const float* W1    = (const float*)d_in[5];
    const float* b1    = (const float*)d_in[6];
    const int* hs0 = (const int*)d_in[7];
    const int* hd0 = (const int*)d_in[8];
    const int* ss0 = (const int*)d_in[9];
    const int* sd0 = (const int*)d_in[10];
    const int* hs1 = (const int*)d_in[11];
    const int* hd1 = (const int*)d_in[12];
    const int* ss1 = (const int*)d_in[13];
    const int* sd1 = (const int*)d_in[14];

    const int n   = in_sizes[0] / D_FEAT;   // 50000
    const int EH  = in_sizes[7];            // 500000
    const int ES  = in_sizes[9];            // 250000
    const int nb2 = (n + 255) / 256;        // 196 dst buckets per etype

    // ---- workspace layout ----
    int* bucketCnt = (int*)d_ws;                       // 4*nb2
    int* rpBucket  = bucketCnt + 4 * nb2;              // 4*(nb2+1)
    int* bcur      = rpBucket + 4 * (nb2 + 1);         // 4*nb2
    int* rpAll     = bcur + 4 * nb2;                   // 4*(n+1)
    int* srcAll    = rpAll + 4 * (size_t)(n + 1);      // 2EH+2ES
    unsigned* recs = (unsigned*)(srcAll + 2 * (size_t)EH + 2 * (size_t)ES); // 2EH+2ES
    size_t int_words = (size_t)12 * nb2 + 4 + 4 * (size_t)(n + 1)
                     + 4 * (size_t)EH + 4 * (size_t)ES;
    int_words = (int_words + 3) & ~(size_t)3;                          // 16 B align
    unsigned short* hb0 = (unsigned short*)((int*)d_ws + int_words);   // n*128 bf16
    unsigned short* db0 = hb0 + (size_t)n * D_FEAT;                    // n*128 bf16
    unsigned short* hb1 = db0 + (size_t)n * D_FEAT;                    // n*128 bf16
    unsigned short* db1 = hb1 + (size_t)n * D_FEAT;                    // n*128 bf16
    unsigned short* z   = db1 + (size_t)n * D_FEAT;                    // n*256 bf16
    unsigned short* Wb0 = z + (size_t)n * K_DIM;                       // 128*256
    unsigned short* Wb1 = Wb0 + 128 * 256;                             // 64*256

    const int* rpH0 = rpAll;
    const int* rpS0 = rpAll + (size_t)(n + 1);
    const int* rpH1 = rpAll + 2 * (size_t)(n + 1);
    const int* rpS1 = rpAll + 3 * (size_t)(n + 1);
    int* srcH0 = srcAll;
    int* srcS0 = srcAll + (size_t)EH;
    int* srcH1 = srcAll + (size_t)EH + ES;
    int* srcS1 = srcAll + 2 * (size_t)EH + ES;

    dim3 blk(256);
    int binb  = (EH + EPB - 1) / EPB;
    int prepb = ((n * 16) + 255) / 256;
    int aggb  = (n + 3) / 4;
    int gemmb0 = (n + 31) / 32;   // 32 rows per block (layer-0 GEMM)
    int gemmb1 = (n + 31) / 32;   // 32 rows per block (layer-1 GEMM, 128 thr)

    // ---- CSR build for BOTH layers + static prep ----
    hipMemsetAsync(bucketCnt, 0, 4 * (size_t)nb2 * sizeof(int), stream);
    conv_weights<<<128, blk, 0, stream>>>(W0, Wb0, W1, Wb1);
    histB<<<dim3(binb, 4), blk, 0, stream>>>(hd0, sd0, hd1, sd1, EH, ES, bucketCnt, nb2);
    scanBuckets<<<4, blk, 0, stream>>>(bucketCnt, rpBucket, bcur, nb2);
    binA<<<dim3(binb, 4), blk, 0, stream>>>(hs0, hd0, ss0, sd0, hs1, hd1, ss1, sd1,
                                            EH, ES, bcur, recs, nb2);
    placeB<<<dim3(nb2, 4), blk, 0, stream>>>(recs, rpBucket, rpAll, srcAll, EH, ES, n, nb2);
    prep_static<<<prepb, blk, 0, stream>>>((const float4*)x, (const float4*)hbar0,
                                           (const float4*)hbar1, (uint4*)hb0, (uint4*)db0,
                                           (uint4*)hb1, (uint4*)z, n * 16);

    // ---------------- Layer 0 ----------------
    aggregate_z<<<aggb, blk, 0, stream>>>((const uint4*)hb0, (const uint4*)db0,
                                          rpH0, srcH0, rpS0, srcS0, (uint4*)z, n);
    gemm_mfma_l0<<<gemmb0, blk, 0, stream>>>(z, Wb0, b0, hbar1, db1, z, n);

    // ---------------- Layer 1 ----------------
    aggregate_z<<<aggb, blk, 0, stream>>>((const uint4*)hb1, (const uint4*)db1,
                                          rpH1, srcH1, rpS1, srcS1, (uint4*)z, n);
    gemm_mfma<3><<<gemmb1, dim3(128), 0, stream>>>(z, Wb1, b1, (float*)d_out, n, 47);
}

// Round 3
// 305.050 us; speedup vs baseline: 1.1290x; 1.0874x over previous
//
#include <hip/hip_runtime.h>

// N=50000, D=128 (both layers), K=256, EH=500000, ES=250000.
#define D_FEAT 128
#define K_DIM  256
#define EPB 4096
#define PADL 136   // LDS leading dim (ushorts) for the 32x128 epilogue tile; 272B row, 16B-aligned

// ---- fragment-major layouts (eliminates 64-line address divergence in GEMMs) ----
// Wb (layer L, NT tiles): slot ((k0*NT + T)*64 + lane) * 8 shorts
//   = W[T*16 + (lane&15)][k0*32 + (lane>>4)*8 .. +8]
// z  (A operand):        slot ((G*8 + k0)*64 + lane) * 8 shorts,  G = row group of 16
//   = z_row[G*16 + (lane&15)][k0*32 + (lane>>4)*8 .. +8]

typedef __attribute__((ext_vector_type(8))) short bf16x8;
typedef __attribute__((ext_vector_type(4))) float f32x4;

__device__ __forceinline__ unsigned short f2b(float f) {
    union { float f; unsigned u; } cv; cv.f = f;
    return (unsigned short)((cv.u + 0x7fffu + ((cv.u >> 16) & 1u)) >> 16);
}

__device__ __forceinline__ unsigned pack2(float lo, float hi) {
    return (unsigned)f2b(lo) | ((unsigned)f2b(hi) << 16);
}

__device__ __forceinline__ uint4 pack8(float4 a, float4 b) {
    return make_uint4(pack2(a.x, a.y), pack2(a.z, a.w), pack2(b.x, b.y), pack2(b.z, b.w));
}

// unpack uint4 = 8 bf16 (low half of word = even element) and accumulate
__device__ __forceinline__ void addu4(float* a, uint4 v) {
    union { unsigned u; float f; } c;
    c.u = v.x << 16;         a[0] += c.f;
    c.u = v.x & 0xffff0000u; a[1] += c.f;
    c.u = v.y << 16;         a[2] += c.f;
    c.u = v.y & 0xffff0000u; a[3] += c.f;
    c.u = v.z << 16;         a[4] += c.f;
    c.u = v.z & 0xffff0000u; a[5] += c.f;
    c.u = v.w << 16;         a[6] += c.f;
    c.u = v.w & 0xffff0000u; a[7] += c.f;
}

__device__ __forceinline__ float blo(unsigned u) { union { unsigned u; float f; } c; c.u = u << 16; return c.f; }
__device__ __forceinline__ float bhi(unsigned u) { union { unsigned u; float f; } c; c.u = u & 0xffff0000u; return c.f; }

// edge-array offset within the concatenated [H0|S0|H1|S1] space
__device__ __forceinline__ long yoff(int y, int EH, int ES) {
    return (long)((y + 1) >> 1) * EH + (long)(y >> 1) * ES;
}

// ---------------- bucket-level CSR build (both layers; y in 0..3) ----------------

__global__ __launch_bounds__(256)
void histB(const int* __restrict__ hd0, const int* __restrict__ sd0,
           const int* __restrict__ hd1, const int* __restrict__ sd1,
           int EH, int ES, int* __restrict__ bucketCnt, int nb2) {
    int y = blockIdx.y;
    const int* d = (y == 0) ? hd0 : (y == 1) ? sd0 : (y == 2) ? hd1 : sd1;
    int E = (y & 1) ? ES : EH;
    __shared__ int cnt[256];
    int t = threadIdx.x;
    cnt[t] = 0;
    __syncthreads();
    int i0 = blockIdx.x * EPB;
    #pragma unroll
    for (int j = 0; j < 16; ++j) {
        int i = i0 + j * 256 + t;
        if (i < E) atomicAdd(&cnt[d[i] >> 8], 1);
    }
    __syncthreads();
    if (t < nb2 && cnt[t] > 0) atomicAdd(&bucketCnt[y * nb2 + t], cnt[t]);
}

// Parallel exclusive scan of the 196 bucket counts per etype (one block per etype).
__global__ __launch_bounds__(256)
void scanBuckets(const int* __restrict__ bucketCnt, int* __restrict__ rpBucket,
                 int* __restrict__ bcur, int nb2) {
    int y = blockIdx.x;
    int t = threadIdx.x;
    __shared__ int sh[256];
    int c = (t < nb2) ? bucketCnt[y * nb2 + t] : 0;
    sh[t] = c;
    __syncthreads();
    for (int o = 1; o < 256; o <<= 1) {
        int x = (t >= o) ? sh[t - o] : 0;
        __syncthreads();
        sh[t] += x;
        __syncthreads();
    }
    int excl = t ? sh[t - 1] : 0;
    if (t < nb2) {
        rpBucket[y * (nb2 + 1) + t] = excl;
        bcur[y * nb2 + t] = excl;
    }
    if (t == 0) rpBucket[y * (nb2 + 1) + nb2] = sh[255];  // total = E
}

// Record: src (24 bits) | localDst (8 bits) << 24.
__global__ __launch_bounds__(256)
void binA(const int* __restrict__ hs0, const int* __restrict__ hd0,
          const int* __restrict__ ss0, const int* __restrict__ sd0,
          const int* __restrict__ hs1, const int* __restrict__ hd1,
          const int* __restrict__ ss1, const int* __restrict__ sd1,
          int EH, int ES, int* __restrict__ bcur, unsigned* __restrict__ recs,
          int nb2) {
    int y = blockIdx.y;
    const int* src = (y == 0) ? hs0 : (y == 1) ? ss0 : (y == 2) ? hs1 : ss1;
    const int* dst = (y == 0) ? hd0 : (y == 1) ? sd0 : (y == 2) ? hd1 : sd1;
    int E = (y & 1) ? ES : EH;
    unsigned* rb = recs + yoff(y, EH, ES);

    __shared__ int cnt[256];
    int t = threadIdx.x;
    cnt[t] = 0;
    __syncthreads();
    int i0 = blockIdx.x * EPB;
    #pragma unroll
    for (int j = 0; j < 16; ++j) {
        int i = i0 + j * 256 + t;
        if (i < E) atomicAdd(&cnt[dst[i] >> 8], 1);
    }
    __syncthreads();
    int c = cnt[t];
    __syncthreads();
    if (t < nb2 && c > 0) cnt[t] = atomicAdd(&bcur[y * nb2 + t], c);
    __syncthreads();
    #pragma unroll
    for (int j = 0; j < 16; ++j) {
        int i = i0 + j * 256 + t;
        if (i < E) {
            int dd = dst[i];
            int slot = atomicAdd(&cnt[dd >> 8], 1);
            rb[slot] = (unsigned)src[i] | ((unsigned)(dd & 255) << 24);
        }
    }
}

__global__ __launch_bounds__(256)
void placeB(const unsigned* __restrict__ recs, const int* __restrict__ rpBucket,
            int* __restrict__ rpAll, int* __restrict__ srcAll,
            int EH, int ES, int n, int nb2) {
    int y = blockIdx.y;
    int b = blockIdx.x;
    int E = (y & 1) ? ES : EH;
    int* rp = rpAll + (size_t)y * (n + 1);
    long off = yoff(y, EH, ES);
    const unsigned* rb = recs + off;
    int* sb = srcAll + off;
    int e0 = rpBucket[y * (nb2 + 1) + b];
    int e1 = rpBucket[y * (nb2 + 1) + b + 1];
    int nodeBase = b << 8;

    __shared__ int cnt[256];
    __shared__ int sh[256];
    int t = threadIdx.x;
    cnt[t] = 0;
    __syncthreads();
    for (int e = e0 + t; e < e1; e += 256)
        atomicAdd(&cnt[rb[e] >> 24], 1);
    __syncthreads();
    sh[t] = cnt[t];
    __syncthreads();
    for (int o = 1; o < 256; o <<= 1) {
        int x = (t >= o) ? sh[t - o] : 0;
        __syncthreads();
        sh[t] += x;
        __syncthreads();
    }
    int base = e0 + (t ? sh[t - 1] : 0);
    if (nodeBase + t < n) rp[nodeBase + t] = base;
    if (b == 0 && t == 0) rp[n] = E;
    cnt[t] = base;
    __syncthreads();
    for (int e = e0 + t; e < e1; e += 256) {
        unsigned r = rb[e];
        int p = atomicAdd(&cnt[r >> 24], 1);
        sb[p] = (int)(r & 0x00FFFFFFu);
    }
}

// ---------------- upfront bf16 prep ----------------
// hb0/db0/hb1 stay row-major (gather targets); z left half written fragment-major.
__global__ __launch_bounds__(256)
void prep_static(const float4* __restrict__ x, const float4* __restrict__ hbar0,
                 const float4* __restrict__ hbar1,
                 uint4* __restrict__ hb0, uint4* __restrict__ db0,
                 uint4* __restrict__ hb1, uint4* __restrict__ z, int n16) {
    int i = blockIdx.x * 256 + threadIdx.x;
    if (i >= n16) return;
    float4 xa = x[i * 2],     xb = x[i * 2 + 1];
    float4 ba = hbar0[i * 2], bb = hbar0[i * 2 + 1];
    float4 ca = hbar1[i * 2], cb = hbar1[i * 2 + 1];
    hb0[i] = pack8(ba, bb);
    db0[i] = pack8(make_float4(xa.x - ba.x, xa.y - ba.y, xa.z - ba.z, xa.w - ba.w),
                   make_float4(xb.x - bb.x, xb.y - bb.y, xb.z - bb.z, xb.w - bb.w));
    hb1[i] = pack8(ca, cb);
    int g = i >> 4, seg = i & 15;
    int G = g >> 4, r = g & 15, k0 = seg >> 2, kq = seg & 3;
    z[((size_t)G * 8 + k0) * 64 + kq * 16 + r] = pack8(xa, xb);   // fragment-major
}

// Weights -> fragment-major bf16. Layer0: 8 k0 x 8 T x 64 lanes; layer1: 8 x 3 x 64.
__global__ __launch_bounds__(256)
void conv_weights(const float* __restrict__ W0, unsigned short* __restrict__ WbF0,
                  const float* __restrict__ W1, unsigned short* __restrict__ WbF1) {
    int i = blockIdx.x * 256 + threadIdx.x;
    if (i < 4096) {
        int k0 = i >> 9, T = (i >> 6) & 7, lane = i & 63;
        int col = T * 16 + (lane & 15);
        int kb = k0 * 32 + (lane >> 4) * 8;
        const float* src = W0 + (size_t)col * 256 + kb;
        unsigned short* dst = WbF0 + (size_t)i * 8;
        #pragma unroll
        for (int e = 0; e < 8; ++e) dst[e] = f2b(src[e]);
    }
    if (i < 1536) {
        int k0 = i / 192, rem = i % 192;
        int T = rem >> 6, lane = rem & 63;
        int col = T * 16 + (lane & 15);
        int kb = k0 * 32 + (lane >> 4) * 8;
        unsigned short* dst = WbF1 + (size_t)i * 8;
        #pragma unroll
        for (int e = 0; e < 8; ++e)
            dst[e] = (col < 47) ? f2b(W1[(size_t)col * 256 + kb + e]) : (unsigned short)0;
    }
}

// ---------------- aggregation: one full wave per node ----------------
__global__ __launch_bounds__(256)
void aggregate_z(const uint4* __restrict__ HB, const uint4* __restrict__ DB,
                 const int* __restrict__ rpH, const int* __restrict__ srcH,
                 const int* __restrict__ rpS, const int* __restrict__ srcS,
                 uint4* __restrict__ z, int n) {
    int g = blockIdx.x * 4 + (threadIdx.x >> 6);
    if (g >= n) return;
    int lane = threadIdx.x & 63;
    int j = lane >> 4, l = lane & 15;

    int hb_ = rpH[g], he = rpH[g + 1];
    int sb  = rpS[g], se = rpS[g + 1];

    float a[8] = {0, 0, 0, 0, 0, 0, 0, 0};
    for (int e0 = hb_; e0 < he; e0 += 8) {
        int e1 = e0 + j, e2 = e0 + 4 + j;
        uint4 v1 = make_uint4(0, 0, 0, 0), v2 = make_uint4(0, 0, 0, 0);
        if (e1 < he) v1 = HB[(size_t)srcH[e1] * 16 + l];
        if (e2 < he) v2 = HB[(size_t)srcH[e2] * 16 + l];
        addu4(a, v1); addu4(a, v2);
    }
    float d[8] = {0, 0, 0, 0, 0, 0, 0, 0};
    for (int e0 = sb; e0 < se; e0 += 8) {
        int e1 = e0 + j, e2 = e0 + 4 + j;
        uint4 v1 = make_uint4(0, 0, 0, 0), v2 = make_uint4(0, 0, 0, 0);
        if (e1 < se) v1 = DB[(size_t)srcS[e1] * 16 + l];
        if (e2 < se) v2 = DB[(size_t)srcS[e2] * 16 + l];
        addu4(d, v1); addu4(d, v2);
    }

    float rH = 1.0f / fmaxf((float)(he - hb_), 1.0f);
    float rS = 1.0f / fmaxf((float)(se - sb), 1.0f);
    float s[8];
    #pragma unroll
    for (int i = 0; i < 8; ++i) {
        float v = a[i] * rH + d[i] * rS;
        v += __shfl_xor(v, 16);
        v += __shfl_xor(v, 32);
        s[i] = v;
    }
    if (j == 0) {
        // lane l holds k = 128 + l*8 .. +8  ->  fragment slot
        uint4 rv = make_uint4(pack2(s[0], s[1]), pack2(s[2], s[3]),
                              pack2(s[4], s[5]), pack2(s[6], s[7]));
        size_t slot = ((size_t)(g >> 4) * 8 + 4 + (l >> 2)) * 64 + (l & 3) * 16 + (g & 15);
        z[slot] = rv;
    }
}

// ---------------- MFMA GEMM layer 0: fused epilogue (LDS-transposed) ----------------
// Block: 256 thr = 4 waves; 32 rows/block. Wave (rt,ch): rows rt*16..+16, cols ch*64..+64.
// A and B read from fragment-major buffers: every load = contiguous 1KiB per wave.
__global__ __launch_bounds__(256, 2)
void gemm_mfma_l0(const unsigned short* __restrict__ Z, const unsigned short* __restrict__ Wb,
                  const float* __restrict__ bias, const float* __restrict__ hbar1,
                  unsigned short* __restrict__ db1, unsigned short* __restrict__ zl, int n) {
    __shared__ unsigned short hl[32 * PADL];
    int tid  = threadIdx.x;
    int wave = tid >> 6;
    int lane = tid & 63;
    int rt = wave >> 1;                 // row tile 0..1
    int ch = wave & 1;                  // col half 0..1
    int m0 = blockIdx.x * 32;
    int cl = lane & 15;
    int kq = lane >> 4;

    const short* Af = (const short*)Z;
    const short* Bf = (const short*)Wb;
    size_t G = (size_t)(m0 >> 4) + rt;

    // A row-slice: 8 coalesced fragment loads (32 VGPR, all in flight)
    bf16x8 aF[8];
    #pragma unroll
    for (int k0 = 0; k0 < 8; ++k0)
        aF[k0] = *(const bf16x8*)(Af + ((G * 8 + k0) * 64 + lane) * 8);

    f32x4 acc[4] = {};
    bf16x8 bF[2][4];
    #pragma unroll
    for (int t = 0; t < 4; ++t)
        bF[0][t] = *(const bf16x8*)(Bf + ((size_t)((0 * 8 + ch * 4 + t)) * 64 + lane) * 8);

    #pragma unroll
    for (int k0 = 0; k0 < 8; ++k0) {
        int cur = k0 & 1, nxt = cur ^ 1;
        if (k0 < 7) {
            #pragma unroll
            for (int t = 0; t < 4; ++t)
                bF[nxt][t] = *(const bf16x8*)(Bf + ((size_t)(((k0 + 1) * 8 + ch * 4 + t)) * 64 + lane) * 8);
        }
        #pragma unroll
        for (int t = 0; t < 4; ++t)
            acc[t] = __builtin_amdgcn_mfma_f32_16x16x32_bf16(aF[k0], bF[cur][t], acc[t], 0, 0, 0);
    }

    // stage h = relu(acc + bias) into LDS tile [32][PADL] (bf16)
    #pragma unroll
    for (int t = 0; t < 4; ++t) {
        int c = ch * 64 + t * 16 + cl;
        float bv = bias[c];
        #pragma unroll
        for (int r = 0; r < 4; ++r) {
            int row = rt * 16 + kq * 4 + r;
            hl[row * PADL + c] = f2b(fmaxf(acc[t][r] + bv, 0.0f));
        }
    }
    __syncthreads();

    // zl (layer-1 A operand) written FRAGMENT-MAJOR: 512 slots of 16B, coalesced.
    #pragma unroll
    for (int s = 0; s < 2; ++s) {
        int ls = tid + s * 256;
        int gi = ls >> 8, k0 = (ls >> 6) & 3, ln = ls & 63;
        int rl = gi * 16 + (ln & 15);
        int col = k0 * 32 + (ln >> 4) * 8;
        int m = m0 + rl;
        if (m < n) {
            uint4 v = *(const uint4*)(hl + rl * PADL + col);
            ((uint4*)zl)[((size_t)(m0 >> 4) + gi) * 8 * 64 + (size_t)k0 * 64 + ln] = v;
        }
    }

    // db1 = bf16(h - hbar1), row-major (gather target), coalesced
    int row  = tid >> 3;
    int col  = (tid & 7) * 16;
    int m    = m0 + row;
    if (m < n) {
        const uint4* hr = (const uint4*)(hl + row * PADL + col);
        uint4 v0 = hr[0];
        uint4 v1 = hr[1];
        const float4* hb = (const float4*)(hbar1 + (size_t)m * 128 + col);
        float4 h0 = hb[0], h1 = hb[1], h2 = hb[2], h3 = hb[3];
        uint4 d0, d1;
        d0.x = pack2(blo(v0.x) - h0.x, bhi(v0.x) - h0.y);
        d0.y = pack2(blo(v0.y) - h0.z, bhi(v0.y) - h0.w);
        d0.z = pack2(blo(v0.z) - h1.x, bhi(v0.z) - h1.y);
        d0.w = pack2(blo(v0.w) - h1.z, bhi(v0.w) - h1.w);
        d1.x = pack2(blo(v1.x) - h2.x, bhi(v1.x) - h2.y);
        d1.y = pack2(blo(v1.y) - h2.z, bhi(v1.y) - h2.w);
        d1.z = pack2(blo(v1.z) - h3.x, bhi(v1.z) - h3.y);
        d1.w = pack2(blo(v1.w) - h3.z, bhi(v1.w) - h3.w);
        uint4* dp = (uint4*)(db1 + (size_t)m * 128 + col);
        dp[0] = d0;
        dp[1] = d1;
    }
}

// ---------------- MFMA GEMM layer 1 -> f32 out ----------------
// 128-thread blocks (2 waves, 32 rows); fragment-major A and B.
template<int NT>
__global__ __launch_bounds__(128, 2)
void gemm_mfma(const unsigned short* __restrict__ Z, const unsigned short* __restrict__ Wb,
               const float* __restrict__ bias, float* __restrict__ out, int n, int COLS) {
    int wave = threadIdx.x >> 6;
    int lane = threadIdx.x & 63;
    int m0 = blockIdx.x * 32 + wave * 16;
    int cl = lane & 15;
    int kq = lane >> 4;

    const short* Af = (const short*)Z;
    const short* Bf = (const short*)Wb;
    size_t G = (size_t)(m0 >> 4);

    bf16x8 aF[8];
    #pragma unroll
    for (int k0 = 0; k0 < 8; ++k0)
        aF[k0] = *(const bf16x8*)(Af + ((G * 8 + k0) * 64 + lane) * 8);

    f32x4 acc[NT] = {};
    bf16x8 bF[2][NT];
    #pragma unroll
    for (int t = 0; t < NT; ++t)
        bF[0][t] = *(const bf16x8*)(Bf + ((size_t)(0 * NT + t) * 64 + lane) * 8);

    #pragma unroll
    for (int k0 = 0; k0 < 8; ++k0) {
        int cur = k0 & 1, nxt = cur ^ 1;
        if (k0 < 7) {
            #pragma unroll
            for (int t = 0; t < NT; ++t)
                bF[nxt][t] = *(const bf16x8*)(Bf + ((size_t)((k0 + 1) * NT + t) * 64 + lane) * 8);
        }
        #pragma unroll
        for (int t = 0; t < NT; ++t)
            acc[t] = __builtin_amdgcn_mfma_f32_16x16x32_bf16(aF[k0], bF[cur][t], acc[t], 0, 0, 0);
    }

    int rg = kq * 4;
    #pragma unroll
    for (int t = 0; t < NT; ++t) {
        int c = t * 16 + cl;
        if (c >= COLS) continue;
        float bv = bias[c];
        #pragma unroll
        for (int r = 0; r < 4; ++r) {
            int m = m0 + rg + r;
            if (m < n) out[(size_t)m * COLS + c] = fmaxf(acc[t][r] + bv, 0.f);
        }
    }
}

extern "C" void kernel_launch(void* const* d_in, const int* in_sizes, int n_in,
                              void* d_out, int out_size, void* d_ws, size_t ws_size,
                              hipStream_t stream) {
    const float* x     = (const float*)d_in[0];
    const float* hbar0 = (const float*)d_in[1];
    const float* hbar1 = (const float*)d_in[2];
    const float* W0    = (const float*)d_in[3];
    const float* b0    = (const float*)d_in[4];
    const float* W1    = (const float*)d_in[5];
    const float* b1    = (const float*)d_in[6];
    const int* hs0 = (const int*)d_in[7];
    const int* hd0 = (const int*)d_in[8];
    const int* ss0 = (const int*)d_in[9];
    const int* sd0 = (const int*)d_in[10];
    const int* hs1 = (const int*)d_in[11];
    const int* hd1 = (const int*)d_in[12];
    const int* ss1 = (const int*)d_in[13];
    const int* sd1 = (const int*)d_in[14];

    const int n   = in_sizes[0] / D_FEAT;   // 50000
    const int EH  = in_sizes[7];            // 500000
    const int ES  = in_sizes[9];            // 250000
    const int nb2 = (n + 255) / 256;        // 196 dst buckets per etype

    // ---- workspace layout ----
    int* bucketCnt = (int*)d_ws;                       // 4*nb2
    int* rpBucket  = bucketCnt + 4 * nb2;              // 4*(nb2+1)
    int* bcur      = rpBucket + 4 * (nb2 + 1);         // 4*nb2
    int* rpAll     = bcur + 4 * nb2;                   // 4*(n+1)
    int* srcAll    = rpAll + 4 * (size_t)(n + 1);      // 2EH+2ES
    unsigned* recs = (unsigned*)(srcAll + 2 * (size_t)EH + 2 * (size_t)ES); // 2EH+2ES
    size_t int_words = (size_t)12 * nb2 + 4 + 4 * (size_t)(n + 1)
                     + 4 * (size_t)EH + 4 * (size_t)ES;
    int_words = (int_words + 3) & ~(size_t)3;                          // 16 B align
    unsigned short* hb0 = (unsigned short*)((int*)d_ws + int_words);   // n*128 bf16
    unsigned short* db0 = hb0 + (size_t)n * D_FEAT;                    // n*128 bf16
    unsigned short* hb1 = db0 + (size_t)n * D_FEAT;                    // n*128 bf16
    unsigned short* db1 = hb1 + (size_t)n * D_FEAT;                    // n*128 bf16
    unsigned short* z   = db1 + (size_t)n * D_FEAT;                    // n*256 bf16 (+1 pad group)
    unsigned short* Wb0 = z + (size_t)n * K_DIM + 4096;                // 128*256 (pad: tail group reads)
    unsigned short* Wb1 = Wb0 + 128 * 256;                             // 64*256

    const int* rpH0 = rpAll;
    const int* rpS0 = rpAll + (size_t)(n + 1);
    const int* rpH1 = rpAll + 2 * (size_t)(n + 1);
    const int* rpS1 = rpAll + 3 * (size_t)(n + 1);
    int* srcH0 = srcAll;
    int* srcS0 = srcAll + (size_t)EH;
    int* srcH1 = srcAll + (size_t)EH + ES;
    int* srcS1 = srcAll + 2 * (size_t)EH + ES;

    dim3 blk(256);
    int binb  = (EH + EPB - 1) / EPB;
    int prepb = ((n * 16) + 255) / 256;
    int aggb  = (n + 3) / 4;
    int gemmb0 = (n + 31) / 32;   // 32 rows per block (layer-0 GEMM)
    int gemmb1 = (n + 31) / 32;   // 32 rows per block (layer-1 GEMM, 128 thr)

    // ---- CSR build for BOTH layers + static prep ----
    hipMemsetAsync(bucketCnt, 0, 4 * (size_t)nb2 * sizeof(int), stream);
    conv_weights<<<16, blk, 0, stream>>>(W0, Wb0, W1, Wb1);
    histB<<<dim3(binb, 4), blk, 0, stream>>>(hd0, sd0, hd1, sd1, EH, ES, bucketCnt, nb2);
    scanBuckets<<<4, blk, 0, stream>>>(bucketCnt, rpBucket, bcur, nb2);
    binA<<<dim3(binb, 4), blk, 0, stream>>>(hs0, hd0, ss0, sd0, hs1, hd1, ss1, sd1,
                                            EH, ES, bcur, recs, nb2);
    placeB<<<dim3(nb2, 4), blk, 0, stream>>>(recs, rpBucket, rpAll, srcAll, EH, ES, n, nb2);
    prep_static<<<prepb, blk, 0, stream>>>((const float4*)x, (const float4*)hbar0,
                                           (const float4*)hbar1, (uint4*)hb0, (uint4*)db0,
                                           (uint4*)hb1, (uint4*)z, n * 16);

    // ---------------- Layer 0 ----------------
    aggregate_z<<<aggb, blk, 0, stream>>>((const uint4*)hb0, (const uint4*)db0,
                                          rpH0, srcH0, rpS0, srcS0, (uint4*)z, n);
    gemm_mfma_l0<<<gemmb0, blk, 0, stream>>>(z, Wb0, b0, hbar1, db1, z, n);

    // ---------------- Layer 1 ----------------
    aggregate_z<<<aggb, blk, 0, stream>>>((const uint4*)hb1, (const uint4*)db1,
                                          rpH1, srcH1, rpS1, srcS1, (uint4*)z, n);
    gemm_mfma<3><<<gemmb1, dim3(128), 0, stream>>>(z, Wb1, b1, (float*)d_out, n, 47);
}

// Round 4
// 300.455 us; speedup vs baseline: 1.1463x; 1.0153x over previous
//
#include <hip/hip_runtime.h>

// N=50000, D=128 (both layers), K=256, EH=500000, ES=250000.
#define D_FEAT 128
#define K_DIM  256
#define EPB 4096
#define PADL 136   // LDS leading dim (ushorts) for the 32x128 epilogue tile; 272B row, 16B-aligned

// ---- fragment-major layouts (eliminates 64-line address divergence in GEMMs) ----
// Wb (layer L, NT tiles): slot ((k0*NT + T)*64 + lane) * 8 shorts
//   = W[T*16 + (lane&15)][k0*32 + (lane>>4)*8 .. +8]
// z  (A operand):        slot ((G*8 + k0)*64 + lane) * 8 shorts,  G = row group of 16
//   = z_row[G*16 + (lane&15)][k0*32 + (lane>>4)*8 .. +8]

typedef __attribute__((ext_vector_type(8))) short bf16x8;
typedef __attribute__((ext_vector_type(4))) float f32x4;
typedef __attribute__((ext_vector_type(2))) float f32x2;

__device__ __forceinline__ unsigned short f2b(float f) {
    union { float f; unsigned u; } cv; cv.f = f;
    return (unsigned short)((cv.u + 0x7fffu + ((cv.u >> 16) & 1u)) >> 16);
}

__device__ __forceinline__ unsigned pack2(float lo, float hi) {
    return (unsigned)f2b(lo) | ((unsigned)f2b(hi) << 16);
}

__device__ __forceinline__ uint4 pack8(float4 a, float4 b) {
    return make_uint4(pack2(a.x, a.y), pack2(a.z, a.w), pack2(b.x, b.y), pack2(b.z, b.w));
}

// unpack one u32 (2 bf16) into a packed float2 -> enables v_pk_add_f32 accumulation
__device__ __forceinline__ f32x2 up2(unsigned u) {
    union { unsigned u; float f; } lo, hi;
    lo.u = u << 16; hi.u = u & 0xffff0000u;
    f32x2 r; r.x = lo.f; r.y = hi.f; return r;
}

__device__ __forceinline__ void addu4p(f32x2* a, uint4 v) {
    a[0] += up2(v.x); a[1] += up2(v.y); a[2] += up2(v.z); a[3] += up2(v.w);
}

__device__ __forceinline__ float blo(unsigned u) { union { unsigned u; float f; } c; c.u = u << 16; return c.f; }
__device__ __forceinline__ float bhi(unsigned u) { union { unsigned u; float f; } c; c.u = u & 0xffff0000u; return c.f; }

// edge-array offset within the concatenated [H0|S0|H1|S1] space
__device__ __forceinline__ long yoff(int y, int EH, int ES) {
    return (long)((y + 1) >> 1) * EH + (long)(y >> 1) * ES;
}

// ---------------- bucket-level CSR build (both layers; y in 0..3) ----------------

__global__ __launch_bounds__(256)
void histB(const int* __restrict__ hd0, const int* __restrict__ sd0,
           const int* __restrict__ hd1, const int* __restrict__ sd1,
           int EH, int ES, int* __restrict__ bucketCnt, int nb2) {
    int y = blockIdx.y;
    const int* d = (y == 0) ? hd0 : (y == 1) ? sd0 : (y == 2) ? hd1 : sd1;
    int E = (y & 1) ? ES : EH;
    __shared__ int cnt[256];
    int t = threadIdx.x;
    cnt[t] = 0;
    __syncthreads();
    int i0 = blockIdx.x * EPB;
    #pragma unroll
    for (int j = 0; j < 16; ++j) {
        int i = i0 + j * 256 + t;
        if (i < E) atomicAdd(&cnt[d[i] >> 8], 1);
    }
    __syncthreads();
    if (t < nb2 && cnt[t] > 0) atomicAdd(&bucketCnt[y * nb2 + t], cnt[t]);
}

// Parallel exclusive scan of the 196 bucket counts per etype (one block per etype).
__global__ __launch_bounds__(256)
void scanBuckets(const int* __restrict__ bucketCnt, int* __restrict__ rpBucket,
                 int* __restrict__ bcur, int nb2) {
    int y = blockIdx.x;
    int t = threadIdx.x;
    __shared__ int sh[256];
    int c = (t < nb2) ? bucketCnt[y * nb2 + t] : 0;
    sh[t] = c;
    __syncthreads();
    for (int o = 1; o < 256; o <<= 1) {
        int x = (t >= o) ? sh[t - o] : 0;
        __syncthreads();
        sh[t] += x;
        __syncthreads();
    }
    int excl = t ? sh[t - 1] : 0;
    if (t < nb2) {
        rpBucket[y * (nb2 + 1) + t] = excl;
        bcur[y * nb2 + t] = excl;
    }
    if (t == 0) rpBucket[y * (nb2 + 1) + nb2] = sh[255];  // total = E
}

// Record: src (24 bits) | localDst (8 bits) << 24.
__global__ __launch_bounds__(256)
void binA(const int* __restrict__ hs0, const int* __restrict__ hd0,
          const int* __restrict__ ss0, const int* __restrict__ sd0,
          const int* __restrict__ hs1, const int* __restrict__ hd1,
          const int* __restrict__ ss1, const int* __restrict__ sd1,
          int EH, int ES, int* __restrict__ bcur, unsigned* __restrict__ recs,
          int nb2) {
    int y = blockIdx.y;
    const int* src = (y == 0) ? hs0 : (y == 1) ? ss0 : (y == 2) ? hs1 : ss1;
    const int* dst = (y == 0) ? hd0 : (y == 1) ? sd0 : (y == 2) ? hd1 : sd1;
    int E = (y & 1) ? ES : EH;
    unsigned* rb = recs + yoff(y, EH, ES);

    __shared__ int cnt[256];
    int t = threadIdx.x;
    cnt[t] = 0;
    __syncthreads();
    int i0 = blockIdx.x * EPB;
    #pragma unroll
    for (int j = 0; j < 16; ++j) {
        int i = i0 + j * 256 + t;
        if (i < E) atomicAdd(&cnt[dst[i] >> 8], 1);
    }
    __syncthreads();
    int c = cnt[t];
    __syncthreads();
    if (t < nb2 && c > 0) cnt[t] = atomicAdd(&bcur[y * nb2 + t], c);
    __syncthreads();
    #pragma unroll
    for (int j = 0; j < 16; ++j) {
        int i = i0 + j * 256 + t;
        if (i < E) {
            int dd = dst[i];
            int slot = atomicAdd(&cnt[dd >> 8], 1);
            rb[slot] = (unsigned)src[i] | ((unsigned)(dd & 255) << 24);
        }
    }
}

__global__ __launch_bounds__(256)
void placeB(const unsigned* __restrict__ recs, const int* __restrict__ rpBucket,
            int* __restrict__ rpAll, int* __restrict__ srcAll,
            int EH, int ES, int n, int nb2) {
    int y = blockIdx.y;
    int b = blockIdx.x;
    int E = (y & 1) ? ES : EH;
    int* rp = rpAll + (size_t)y * (n + 1);
    long off = yoff(y, EH, ES);
    const unsigned* rb = recs + off;
    int* sb = srcAll + off;
    int e0 = rpBucket[y * (nb2 + 1) + b];
    int e1 = rpBucket[y * (nb2 + 1) + b + 1];
    int nodeBase = b << 8;

    __shared__ int cnt[256];
    __shared__ int sh[256];
    int t = threadIdx.x;
    cnt[t] = 0;
    __syncthreads();
    for (int e = e0 + t; e < e1; e += 256)
        atomicAdd(&cnt[rb[e] >> 24], 1);
    __syncthreads();
    sh[t] = cnt[t];
    __syncthreads();
    for (int o = 1; o < 256; o <<= 1) {
        int x = (t >= o) ? sh[t - o] : 0;
        __syncthreads();
        sh[t] += x;
        __syncthreads();
    }
    int base = e0 + (t ? sh[t - 1] : 0);
    if (nodeBase + t < n) rp[nodeBase + t] = base;
    if (b == 0 && t == 0) rp[n] = E;
    cnt[t] = base;
    __syncthreads();
    for (int e = e0 + t; e < e1; e += 256) {
        unsigned r = rb[e];
        int p = atomicAdd(&cnt[r >> 24], 1);
        sb[p] = (int)(r & 0x00FFFFFFu);
    }
}

// ---------------- upfront bf16 prep ----------------
// hb0/db0/hb1 stay row-major (gather targets); z left half written fragment-major.
__global__ __launch_bounds__(256)
void prep_static(const float4* __restrict__ x, const float4* __restrict__ hbar0,
                 const float4* __restrict__ hbar1,
                 uint4* __restrict__ hb0, uint4* __restrict__ db0,
                 uint4* __restrict__ hb1, uint4* __restrict__ z, int n16) {
    int i = blockIdx.x * 256 + threadIdx.x;
    if (i >= n16) return;
    float4 xa = x[i * 2],     xb = x[i * 2 + 1];
    float4 ba = hbar0[i * 2], bb = hbar0[i * 2 + 1];
    float4 ca = hbar1[i * 2], cb = hbar1[i * 2 + 1];
    hb0[i] = pack8(ba, bb);
    db0[i] = pack8(make_float4(xa.x - ba.x, xa.y - ba.y, xa.z - ba.z, xa.w - ba.w),
                   make_float4(xb.x - bb.x, xb.y - bb.y, xb.z - bb.z, xb.w - bb.w));
    hb1[i] = pack8(ca, cb);
    int g = i >> 4, seg = i & 15;
    int G = g >> 4, r = g & 15, k0 = seg >> 2, kq = seg & 3;
    z[((size_t)G * 8 + k0) * 64 + kq * 16 + r] = pack8(xa, xb);   // fragment-major
}

// Weights -> fragment-major bf16. Layer0: 8 k0 x 8 T x 64 lanes; layer1: 8 x 3 x 64.
__global__ __launch_bounds__(256)
void conv_weights(const float* __restrict__ W0, unsigned short* __restrict__ WbF0,
                  const float* __restrict__ W1, unsigned short* __restrict__ WbF1) {
    int i = blockIdx.x * 256 + threadIdx.x;
    if (i < 4096) {
        int k0 = i >> 9, T = (i >> 6) & 7, lane = i & 63;
        int col = T * 16 + (lane & 15);
        int kb = k0 * 32 + (lane >> 4) * 8;
        const float* src = W0 + (size_t)col * 256 + kb;
        unsigned short* dst = WbF0 + (size_t)i * 8;
        #pragma unroll
        for (int e = 0; e < 8; ++e) dst[e] = f2b(src[e]);
    }
    if (i < 1536) {
        int k0 = i / 192, rem = i % 192;
        int T = rem >> 6, lane = rem & 63;
        int col = T * 16 + (lane & 15);
        int kb = k0 * 32 + (lane >> 4) * 8;
        unsigned short* dst = WbF1 + (size_t)i * 8;
        #pragma unroll
        for (int e = 0; e < 8; ++e)
            dst[e] = (col < 47) ? f2b(W1[(size_t)col * 256 + kb + e]) : (unsigned short)0;
    }
}

// ---------------- aggregation: one full wave per node ----------------
// 64 lanes = 4 edges (j = lane>>4) x 16 feature-segments (l = lane&15, 16B each).
// H and S edge streams interleaved in one pipeline (4 feature loads in flight);
// src indices prefetched one iteration ahead; packed f32x2 accumulation.
__global__ __launch_bounds__(256)
void aggregate_z(const uint4* __restrict__ HB, const uint4* __restrict__ DB,
                 const int* __restrict__ rpH, const int* __restrict__ srcH,
                 const int* __restrict__ rpS, const int* __restrict__ srcS,
                 uint4* __restrict__ z, int n) {
    int g = blockIdx.x * 4 + (threadIdx.x >> 6);
    if (g >= n) return;
    int lane = threadIdx.x & 63;
    int j = lane >> 4, l = lane & 15;

    int hb_ = rpH[g], he = rpH[g + 1];
    int sb  = rpS[g], se = rpS[g + 1];
    int dH = he - hb_, dS = se - sb;
    int nIt = max((dH + 7) >> 3, (dS + 7) >> 3);

    f32x2 a[4] = {};
    f32x2 d[4] = {};

    // edge cursors (this lane's j-slot) + prefetched src indices
    int iH1 = hb_ + j, iH2 = hb_ + 4 + j;
    int iS1 = sb + j,  iS2 = sb + 4 + j;
    int sH1 = 0, sH2 = 0, sS1 = 0, sS2 = 0;
    if (iH1 < he) sH1 = srcH[iH1];
    if (iH2 < he) sH2 = srcH[iH2];
    if (iS1 < se) sS1 = srcS[iS1];
    if (iS2 < se) sS2 = srcS[iS2];

    for (int it = 0; it < nIt; ++it) {
        uint4 h1 = make_uint4(0, 0, 0, 0), h2 = make_uint4(0, 0, 0, 0);
        uint4 s1 = make_uint4(0, 0, 0, 0), s2 = make_uint4(0, 0, 0, 0);
        if (iH1 < he) h1 = HB[(size_t)sH1 * 16 + l];
        if (iH2 < he) h2 = HB[(size_t)sH2 * 16 + l];
        if (iS1 < se) s1 = DB[(size_t)sS1 * 16 + l];
        if (iS2 < se) s2 = DB[(size_t)sS2 * 16 + l];
        // prefetch next iteration's src indices (overlaps feature-load latency)
        iH1 += 8; iH2 += 8; iS1 += 8; iS2 += 8;
        if (iH1 < he) sH1 = srcH[iH1];
        if (iH2 < he) sH2 = srcH[iH2];
        if (iS1 < se) sS1 = srcS[iS1];
        if (iS2 < se) sS2 = srcS[iS2];
        addu4p(a, h1); addu4p(a, h2);
        addu4p(d, s1); addu4p(d, s2);
    }

    float rH = 1.0f / fmaxf((float)dH, 1.0f);
    float rS = 1.0f / fmaxf((float)dS, 1.0f);
    float s[8];
    #pragma unroll
    for (int i = 0; i < 4; ++i) {
        float v0 = a[i].x * rH + d[i].x * rS;
        float v1 = a[i].y * rH + d[i].y * rS;
        v0 += __shfl_xor(v0, 16);
        v0 += __shfl_xor(v0, 32);
        v1 += __shfl_xor(v1, 16);
        v1 += __shfl_xor(v1, 32);
        s[2 * i] = v0;
        s[2 * i + 1] = v1;
    }
    if (j == 0) {
        // lane l holds k = 128 + l*8 .. +8  ->  fragment slot
        uint4 rv = make_uint4(pack2(s[0], s[1]), pack2(s[2], s[3]),
                              pack2(s[4], s[5]), pack2(s[6], s[7]));
        size_t slot = ((size_t)(g >> 4) * 8 + 4 + (l >> 2)) * 64 + (l & 3) * 16 + (g & 15);
        z[slot] = rv;
    }
}

// ---------------- MFMA GEMM layer 0: fused epilogue (LDS-transposed) ----------------
// Block: 256 thr = 4 waves; 32 rows/block. Wave (rt,ch): rows rt*16..+16, cols ch*64..+64.
// A and B read from fragment-major buffers: every load = contiguous 1KiB per wave.
__global__ __launch_bounds__(256, 2)
void gemm_mfma_l0(const unsigned short* __restrict__ Z, const unsigned short* __restrict__ Wb,
                  const float* __restrict__ bias, const float* __restrict__ hbar1,
                  unsigned short* __restrict__ db1, unsigned short* __restrict__ zl, int n) {
    __shared__ unsigned short hl[32 * PADL];
    int tid  = threadIdx.x;
    int wave = tid >> 6;
    int lane = tid & 63;
    int rt = wave >> 1;                 // row tile 0..1
    int ch = wave & 1;                  // col half 0..1
    int m0 = blockIdx.x * 32;
    int cl = lane & 15;
    int kq = lane >> 4;

    const short* Af = (const short*)Z;
    const short* Bf = (const short*)Wb;
    size_t G = (size_t)(m0 >> 4) + rt;

    // A row-slice: 8 coalesced fragment loads (32 VGPR, all in flight)
    bf16x8 aF[8];
    #pragma unroll
    for (int k0 = 0; k0 < 8; ++k0)
        aF[k0] = *(const bf16x8*)(Af + ((G * 8 + k0) * 64 + lane) * 8);

    f32x4 acc[4] = {};
    bf16x8 bF[2][4];
    #pragma unroll
    for (int t = 0; t < 4; ++t)
        bF[0][t] = *(const bf16x8*)(Bf + ((size_t)((0 * 8 + ch * 4 + t)) * 64 + lane) * 8);

    #pragma unroll
    for (int k0 = 0; k0 < 8; ++k0) {
        int cur = k0 & 1, nxt = cur ^ 1;
        if (k0 < 7) {
            #pragma unroll
            for (int t = 0; t < 4; ++t)
                bF[nxt][t] = *(const bf16x8*)(Bf + ((size_t)(((k0 + 1) * 8 + ch * 4 + t)) * 64 + lane) * 8);
        }
        #pragma unroll
        for (int t = 0; t < 4; ++t)
            acc[t] = __builtin_amdgcn_mfma_f32_16x16x32_bf16(aF[k0], bF[cur][t], acc[t], 0, 0, 0);
    }

    // stage h = relu(acc + bias) into LDS tile [32][PADL] (bf16)
    #pragma unroll
    for (int t = 0; t < 4; ++t) {
        int c = ch * 64 + t * 16 + cl;
        float bv = bias[c];
        #pragma unroll
        for (int r = 0; r < 4; ++r) {
            int row = rt * 16 + kq * 4 + r;
            hl[row * PADL + c] = f2b(fmaxf(acc[t][r] + bv, 0.0f));
        }
    }
    __syncthreads();

    // zl (layer-1 A operand) written FRAGMENT-MAJOR: 512 slots of 16B, coalesced.
    #pragma unroll
    for (int s = 0; s < 2; ++s) {
        int ls = tid + s * 256;
        int gi = ls >> 8, k0 = (ls >> 6) & 3, ln = ls & 63;
        int rl = gi * 16 + (ln & 15);
        int col = k0 * 32 + (ln >> 4) * 8;
        int m = m0 + rl;
        if (m < n) {
            uint4 v = *(const uint4*)(hl + rl * PADL + col);
            ((uint4*)zl)[((size_t)(m0 >> 4) + gi) * 8 * 64 + (size_t)k0 * 64 + ln] = v;
        }
    }

    // db1 = bf16(h - hbar1), row-major (gather target), coalesced
    int row  = tid >> 3;
    int col  = (tid & 7) * 16;
    int m    = m0 + row;
    if (m < n) {
        const uint4* hr = (const uint4*)(hl + row * PADL + col);
        uint4 v0 = hr[0];
        uint4 v1 = hr[1];
        const float4* hb = (const float4*)(hbar1 + (size_t)m * 128 + col);
        float4 h0 = hb[0], h1 = hb[1], h2 = hb[2], h3 = hb[3];
        uint4 d0, d1;
        d0.x = pack2(blo(v0.x) - h0.x, bhi(v0.x) - h0.y);
        d0.y = pack2(blo(v0.y) - h0.z, bhi(v0.y) - h0.w);
        d0.z = pack2(blo(v0.z) - h1.x, bhi(v0.z) - h1.y);
        d0.w = pack2(blo(v0.w) - h1.z, bhi(v0.w) - h1.w);
        d1.x = pack2(blo(v1.x) - h2.x, bhi(v1.x) - h2.y);
        d1.y = pack2(blo(v1.y) - h2.z, bhi(v1.y) - h2.w);
        d1.z = pack2(blo(v1.z) - h3.x, bhi(v1.z) - h3.y);
        d1.w = pack2(blo(v1.w) - h3.z, bhi(v1.w) - h3.w);
        uint4* dp = (uint4*)(db1 + (size_t)m * 128 + col);
        dp[0] = d0;
        dp[1] = d1;
    }
}

// ---------------- MFMA GEMM layer 1 -> f32 out ----------------
// 128-thread blocks (2 waves, 32 rows); fragment-major A and B.
template<int NT>
__global__ __launch_bounds__(128, 2)
void gemm_mfma(const unsigned short* __restrict__ Z, const unsigned short* __restrict__ Wb,
               const float* __restrict__ bias, float* __restrict__ out, int n, int COLS) {
    int wave = threadIdx.x >> 6;
    int lane = threadIdx.x & 63;
    int m0 = blockIdx.x * 32 + wave * 16;
    int cl = lane & 15;
    int kq = lane >> 4;

    const short* Af = (const short*)Z;
    const short* Bf = (const short*)Wb;
    size_t G = (size_t)(m0 >> 4);

    bf16x8 aF[8];
    #pragma unroll
    for (int k0 = 0; k0 < 8; ++k0)
        aF[k0] = *(const bf16x8*)(Af + ((G * 8 + k0) * 64 + lane) * 8);

    f32x4 acc[NT] = {};
    bf16x8 bF[2][NT];
    #pragma unroll
    for (int t = 0; t < NT; ++t)
        bF[0][t] = *(const bf16x8*)(Bf + ((size_t)(0 * NT + t) * 64 + lane) * 8);

    #pragma unroll
    for (int k0 = 0; k0 < 8; ++k0) {
        int cur = k0 & 1, nxt = cur ^ 1;
        if (k0 < 7) {
            #pragma unroll
            for (int t = 0; t < NT; ++t)
                bF[nxt][t] = *(const bf16x8*)(Bf + ((size_t)((k0 + 1) * NT + t) * 64 + lane) * 8);
        }
        #pragma unroll
        for (int t = 0; t < NT; ++t)
            acc[t] = __builtin_amdgcn_mfma_f32_16x16x32_bf16(aF[k0], bF[cur][t], acc[t], 0, 0, 0);
    }

    int rg = kq * 4;
    #pragma unroll
    for (int t = 0; t < NT; ++t) {
        int c = t * 16 + cl;
        if (c >= COLS) continue;
        float bv = bias[c];
        #pragma unroll
        for (int r = 0; r < 4; ++r) {
            int m = m0 + rg + r;
            if (m < n) out[(size_t)m * COLS + c] = fmaxf(acc[t][r] + bv, 0.f);
        }
    }
}

extern "C" void kernel_launch(void* const* d_in, const int* in_sizes, int n_in,
                              void* d_out, int out_size, void* d_ws, size_t ws_size,
                              hipStream_t stream) {
    const float* x     = (const float*)d_in[0];
    const float* hbar0 = (const float*)d_in[1];
    const float* hbar1 = (const float*)d_in[2];
    const float* W0    = (const float*)d_in[3];
    const float* b0    = (const float*)d_in[4];
    const float* W1    = (const float*)d_in[5];
    const float* b1    = (const float*)d_in[6];
    const int* hs0 = (const int*)d_in[7];
    const int* hd0 = (const int*)d_in[8];
    const int* ss0 = (const int*)d_in[9];
    const int* sd0 = (const int*)d_in[10];
    const int* hs1 = (const int*)d_in[11];
    const int* hd1 = (const int*)d_in[12];
    const int* ss1 = (const int*)d_in[13];
    const int* sd1 = (const int*)d_in[14];

    const int n   = in_sizes[0] / D_FEAT;   // 50000
    const int EH  = in_sizes[7];            // 500000
    const int ES  = in_sizes[9];            // 250000
    const int nb2 = (n + 255) / 256;        // 196 dst buckets per etype

    // ---- workspace layout ----
    int* bucketCnt = (int*)d_ws;                       // 4*nb2
    int* rpBucket  = bucketCnt + 4 * nb2;              // 4*(nb2+1)
    int* bcur      = rpBucket + 4 * (nb2 + 1);         // 4*nb2
    int* rpAll     = bcur + 4 * nb2;                   // 4*(n+1)
    int* srcAll    = rpAll + 4 * (size_t)(n + 1);      // 2EH+2ES
    unsigned* recs = (unsigned*)(srcAll + 2 * (size_t)EH + 2 * (size_t)ES); // 2EH+2ES
    size_t int_words = (size_t)12 * nb2 + 4 + 4 * (size_t)(n + 1)
                     + 4 * (size_t)EH + 4 * (size_t)ES;
    int_words = (int_words + 3) & ~(size_t)3;                          // 16 B align
    unsigned short* hb0 = (unsigned short*)((int*)d_ws + int_words);   // n*128 bf16
    unsigned short* db0 = hb0 + (size_t)n * D_FEAT;                    // n*128 bf16
    unsigned short* hb1 = db0 + (size_t)n * D_FEAT;                    // n*128 bf16
    unsigned short* db1 = hb1 + (size_t)n * D_FEAT;                    // n*128 bf16
    unsigned short* z   = db1 + (size_t)n * D_FEAT;                    // n*256 bf16 (+1 pad group)
    unsigned short* Wb0 = z + (size_t)n * K_DIM + 4096;                // 128*256 (pad: tail group reads)
    unsigned short* Wb1 = Wb0 + 128 * 256;                             // 64*256

    const int* rpH0 = rpAll;
    const int* rpS0 = rpAll + (size_t)(n + 1);
    const int* rpH1 = rpAll + 2 * (size_t)(n + 1);
    const int* rpS1 = rpAll + 3 * (size_t)(n + 1);
    int* srcH0 = srcAll;
    int* srcS0 = srcAll + (size_t)EH;
    int* srcH1 = srcAll + (size_t)EH + ES;
    int* srcS1 = srcAll + 2 * (size_t)EH + ES;

    dim3 blk(256);
    int binb  = (EH + EPB - 1) / EPB;
    int prepb = ((n * 16) + 255) / 256;
    int aggb  = (n + 3) / 4;
    int gemmb0 = (n + 31) / 32;   // 32 rows per block (layer-0 GEMM)
    int gemmb1 = (n + 31) / 32;   // 32 rows per block (layer-1 GEMM, 128 thr)

    // ---- CSR build for BOTH layers + static prep ----
    hipMemsetAsync(bucketCnt, 0, 4 * (size_t)nb2 * sizeof(int), stream);
    conv_weights<<<16, blk, 0, stream>>>(W0, Wb0, W1, Wb1);
    histB<<<dim3(binb, 4), blk, 0, stream>>>(hd0, sd0, hd1, sd1, EH, ES, bucketCnt, nb2);
    scanBuckets<<<4, blk, 0, stream>>>(bucketCnt, rpBucket, bcur, nb2);
    binA<<<dim3(binb, 4), blk, 0, stream>>>(hs0, hd0, ss0, sd0, hs1, hd1, ss1, sd1,
                                            EH, ES, bcur, recs, nb2);
    placeB<<<dim3(nb2, 4), blk, 0, stream>>>(recs, rpBucket, rpAll, srcAll, EH, ES, n, nb2);
    prep_static<<<prepb, blk, 0, stream>>>((const float4*)x, (const float4*)hbar0,
                                           (const float4*)hbar1, (uint4*)hb0, (uint4*)db0,
                                           (uint4*)hb1, (uint4*)z, n * 16);

    // ---------------- Layer 0 ----------------
    aggregate_z<<<aggb, blk, 0, stream>>>((const uint4*)hb0, (const uint4*)db0,
                                          rpH0, srcH0, rpS0, srcS0, (uint4*)z, n);
    gemm_mfma_l0<<<gemmb0, blk, 0, stream>>>(z, Wb0, b0, hbar1, db1, z, n);

    // ---------------- Layer 1 ----------------
    aggregate_z<<<aggb, blk, 0, stream>>>((const uint4*)hb1, (const uint4*)db1,
                                          rpH1, srcH1, rpS1, srcS1, (uint4*)z, n);
    gemm_mfma<3><<<gemmb1, dim3(128), 0, stream>>>(z, Wb1, b1, (float*)d_out, n, 47);
}